// Round 5
// baseline (2036.623 us; speedup 1.0000x reference)
//
#include <hip/hip_runtime.h>
#include <math.h>

#define NEG_SLOPE 0.2f
__device__ __forceinline__ float lrelu(float x) { return x > 0.f ? x : NEG_SLOPE * x; }

// Order-preserving float<->uint encoding so unsigned atomicMax == float max.
__device__ __forceinline__ unsigned encf(float f) {
    unsigned u = __float_as_uint(f);
    return (u & 0x80000000u) ? ~u : (u | 0x80000000u);
}
__device__ __forceinline__ float decf(unsigned u) {
    return __uint_as_float((u & 0x80000000u) ? (u ^ 0x80000000u) : ~u);
}

__global__ void initK(int* __restrict__ deg, unsigned* __restrict__ gmax1,
                      unsigned* __restrict__ gmax2, int N) {
    int i = blockIdx.x * blockDim.x + threadIdx.x;
    if (i < N) deg[i] = 0;
    if (i < 4) gmax1[i] = 0u;
    if (i == 0) gmax2[0] = 0u;
}

// Phase A: h1 = x @ W1 [N,64]; alpha_src/dst [N,4]; self-loop logit.
__global__ void phaseA(const float* __restrict__ x, const float* __restrict__ W1,
                       const float* __restrict__ a_src, const float* __restrict__ a_dst,
                       float* __restrict__ h1, float* __restrict__ asrc1,
                       float* __restrict__ adst1, float* __restrict__ eloop1, int N) {
    int node = blockIdx.x * 4 + (threadIdx.x >> 6);
    if (node >= N) return;
    int lane = threadIdx.x & 63;
    int head = lane >> 4, c = lane & 15;

    float h = 0.f;
    #pragma unroll
    for (int k = 0; k < 7; k++) h += x[node * 7 + k] * W1[k * 64 + lane];
    h1[node * 64 + lane] = h;

    float s = h * a_src[lane];
    float d = h * a_dst[lane];
    #pragma unroll
    for (int m = 8; m >= 1; m >>= 1) {
        s += __shfl_xor(s, m);
        d += __shfl_xor(d, m);
    }
    if (c == 0) {
        asrc1[node * 4 + head] = s;
        adst1[node * 4 + head] = d;
        eloop1[node * 4 + head] = lrelu(s + d);
    }
}

// Global per-head max of asrc1 [N,4] -> gmax1[4] (encoded).
__global__ void gmax1K(const float* __restrict__ asrc1, unsigned* __restrict__ gmax1, int N) {
    float m0 = -1e30f, m1 = -1e30f, m2 = -1e30f, m3 = -1e30f;
    for (int i = blockIdx.x * blockDim.x + threadIdx.x; i < N; i += gridDim.x * blockDim.x) {
        float4 v = ((const float4*)asrc1)[i];
        m0 = fmaxf(m0, v.x); m1 = fmaxf(m1, v.y);
        m2 = fmaxf(m2, v.z); m3 = fmaxf(m3, v.w);
    }
    #pragma unroll
    for (int mm = 32; mm >= 1; mm >>= 1) {
        m0 = fmaxf(m0, __shfl_xor(m0, mm));
        m1 = fmaxf(m1, __shfl_xor(m1, mm));
        m2 = fmaxf(m2, __shfl_xor(m2, mm));
        m3 = fmaxf(m3, __shfl_xor(m3, mm));
    }
    if ((threadIdx.x & 63) == 0) {
        atomicMax(&gmax1[0], encf(m0));
        atomicMax(&gmax1[1], encf(m1));
        atomicMax(&gmax1[2], encf(m2));
        atomicMax(&gmax1[3], encf(m3));
    }
}

__global__ void gmax2K(const float* __restrict__ asrc2, unsigned* __restrict__ gmax2, int N) {
    float m0 = -1e30f;
    for (int i = blockIdx.x * blockDim.x + threadIdx.x; i < N; i += gridDim.x * blockDim.x)
        m0 = fmaxf(m0, asrc2[i]);
    #pragma unroll
    for (int mm = 32; mm >= 1; mm >>= 1) m0 = fmaxf(m0, __shfl_xor(m0, mm));
    if ((threadIdx.x & 63) == 0) atomicMax(gmax2, encf(m0));
}

__global__ void degCount(const int* __restrict__ dst, int* __restrict__ deg, int E) {
    int i = blockIdx.x * blockDim.x + threadIdx.x;
    if (i < E) atomicAdd(&deg[dst[i]], 1);
}

__global__ void scan1(const int* __restrict__ deg, int* __restrict__ rowstart,
                      int* __restrict__ blockSum, int N) {
    __shared__ int sm[256];
    int tid = threadIdx.x;
    int i = blockIdx.x * 256 + tid;
    int v = (i < N) ? deg[i] : 0;
    sm[tid] = v;
    __syncthreads();
    for (int off = 1; off < 256; off <<= 1) {
        int t = sm[tid];
        int add = (tid >= off) ? sm[tid - off] : 0;
        __syncthreads();
        sm[tid] = t + add;
        __syncthreads();
    }
    if (i < N) rowstart[i] = sm[tid] - v;     // exclusive
    if (tid == 255) blockSum[blockIdx.x] = sm[255];
}

__global__ void scan2(int* __restrict__ blockSum, int nb) {
    __shared__ int sm[1024];
    int tid = threadIdx.x;
    int v = (tid < nb) ? blockSum[tid] : 0;
    sm[tid] = v;
    __syncthreads();
    for (int off = 1; off < 1024; off <<= 1) {
        int t = sm[tid];
        int add = (tid >= off) ? sm[tid - off] : 0;
        __syncthreads();
        sm[tid] = t + add;
        __syncthreads();
    }
    if (tid < nb) blockSum[tid] = sm[tid] - v;  // exclusive
}

__global__ void scan3(int* __restrict__ rowstart, const int* __restrict__ blockSum, int N) {
    int i = blockIdx.x * 256 + threadIdx.x;
    if (i < N) rowstart[i] += blockSum[blockIdx.x];
}

// Bucket bases from rowstart (bucket = 128 nodes); zero bucket cursors.
__global__ void bbaseK(const int* __restrict__ rowstart, int* __restrict__ bbase,
                       int* __restrict__ bcur, int nbuck, int N, int E) {
    int i = blockIdx.x * blockDim.x + threadIdx.x;
    if (i <= nbuck) bbase[i] = (i * 128 < N) ? rowstart[i * 128] : E;
    if (i < nbuck) bcur[i] = 0;
}

// Scatter P1: pack (src,dst) into bucket-ordered ebuf. Writes within a bucket
// are sequential -> 64B lines fill in a tight window (L2-assembled).
__global__ void scatterP1(const int* __restrict__ src, const int* __restrict__ dst,
                          const int* __restrict__ bbase, int* __restrict__ bcur,
                          int2* __restrict__ ebuf, int E) {
    int i = blockIdx.x * blockDim.x + threadIdx.x;
    if (i >= E) return;
    int d = dst[i];
    int b = d >> 7;
    int pos = atomicAdd(&bcur[b], 1);
    ebuf[bbase[b] + pos] = make_int2(src[i], d);
}

// Scatter P2: one workgroup per bucket. Coalesced ebuf read, LDS per-node
// cursor, csr writes confined to this bucket's ~16KB window on ONE CU.
__global__ void scatterP2(const int2* __restrict__ ebuf, const int* __restrict__ bbase,
                          const int* __restrict__ rowstart, int* __restrict__ csr) {
    int b = blockIdx.x;
    int beg = bbase[b], end = bbase[b + 1];
    __shared__ int lcur[128];
    if (threadIdx.x < 128) lcur[threadIdx.x] = 0;
    __syncthreads();
    int base = b << 7;
    for (int i = beg + threadIdx.x; i < end; i += blockDim.x) {
        int2 e = ebuf[i];
        int pos = rowstart[e.y] + atomicAdd(&lcur[e.y - base], 1);
        csr[pos] = e.x;
    }
}

// Layer-1 gather: 16 lanes per node (lane t owns channels 4t..4t+3, head=t>>2),
// 4 nodes per wave -> 4 independent gather streams. Single pass (gmax bound).
// Fused epilogue: normalize, +b1, ELU, @W2, layer-2 logits, pack h2pad row.
__global__ void gatherL1(const int* __restrict__ csr, const int* __restrict__ rowstart,
                         const int* __restrict__ deg, const unsigned* __restrict__ gmax1,
                         const float* __restrict__ h1, const float* __restrict__ asrc1,
                         const float* __restrict__ adst1, const float* __restrict__ eloop1,
                         const float* __restrict__ b1, const float* __restrict__ W2,
                         const float* __restrict__ a_src2, const float* __restrict__ a_dst2,
                         float* __restrict__ h2pad, float* __restrict__ asrc2,
                         float* __restrict__ adst2, float* __restrict__ eloop2, int N) {
    int node = blockIdx.x * 16 + (threadIdx.x >> 4);
    if (node >= N) return;
    int t = threadIdx.x & 15;
    int head = t >> 2;

    int rs = rowstart[node], dg = deg[node];
    float adh = adst1[node * 4 + head];
    float el = eloop1[node * 4 + head];
    float m = lrelu(decf(gmax1[head]) + adh);   // upper bound on segment logits

    const float4* h1v = (const float4*)h1;      // h1 as [N][16] of float4
    float z0 = __expf(el - m);
    float den = z0;
    float4 hv0 = h1v[(size_t)node * 16 + t];
    float ax = z0 * hv0.x, ay = z0 * hv0.y, az = z0 * hv0.z, aw = z0 * hv0.w;

    if (dg > 0) {
        int s = csr[rs];
        for (int k = rs; k < rs + dg; ++k) {
            int kk = (k + 1 < rs + dg) ? k + 1 : k;
            int s_next = csr[kk];
            float av = asrc1[s * 4 + head];
            float4 hv = h1v[(size_t)s * 16 + t];
            float z = __expf(lrelu(av + adh) - m);
            den += z;
            ax = fmaf(z, hv.x, ax); ay = fmaf(z, hv.y, ay);
            az = fmaf(z, hv.z, az); aw = fmaf(z, hv.w, aw);
            s = s_next;
        }
    }

    float inv = 1.f / den;
    float4 bv = ((const float4*)b1)[t];
    float v0 = ax * inv + bv.x, v1 = ay * inv + bv.y;
    float v2 = az * inv + bv.z, v3 = aw * inv + bv.w;
    v0 = v0 > 0.f ? v0 : __expf(v0) - 1.f;
    v1 = v1 > 0.f ? v1 : __expf(v1) - 1.f;
    v2 = v2 > 0.f ? v2 : __expf(v2) - 1.f;
    v3 = v3 > 0.f ? v3 : __expf(v3) - 1.f;

    // h2 = v @ W2 (64->6): per-lane partial over 4 channels, reduce over 16 lanes
    float hh[6];
    #pragma unroll
    for (int c2 = 0; c2 < 6; c2++) {
        float p = v0 * W2[(t * 4 + 0) * 6 + c2] + v1 * W2[(t * 4 + 1) * 6 + c2]
                + v2 * W2[(t * 4 + 2) * 6 + c2] + v3 * W2[(t * 4 + 3) * 6 + c2];
        #pragma unroll
        for (int mm = 8; mm >= 1; mm >>= 1) p += __shfl_xor(p, mm);
        hh[c2] = p;
    }
    float as = 0.f, ad = 0.f;
    #pragma unroll
    for (int c2 = 0; c2 < 6; c2++) {
        as += hh[c2] * a_src2[c2];
        ad += hh[c2] * a_dst2[c2];
    }
    if (t == 0) {
        #pragma unroll
        for (int c2 = 0; c2 < 6; c2++) h2pad[(size_t)node * 8 + c2] = hh[c2];
        h2pad[(size_t)node * 8 + 6] = as;   // asrc2 packed into the gather row
        asrc2[node] = as;
        adst2[node] = ad;
        eloop2[node] = lrelu(as + ad);
    }
}

// Layer-2 gather + log_softmax. Wave per node, lane per edge (64 in flight).
// One 32B gather per edge (h2pad row holds h2[0..5] and asrc2).
__global__ void gatherL2(const int* __restrict__ csr, const int* __restrict__ rowstart,
                         const int* __restrict__ deg, const unsigned* __restrict__ gmax2,
                         const float* __restrict__ h2pad, const float* __restrict__ adst2,
                         const float* __restrict__ eloop2,
                         const float* __restrict__ b2, float* __restrict__ out, int N) {
    int node = blockIdx.x * 4 + (threadIdx.x >> 6);
    if (node >= N) return;
    int lane = threadIdx.x & 63;
    int rs = rowstart[node], ke = rs + deg[node];

    float adn = adst2[node];
    float m = lrelu(decf(*gmax2) + adn);

    float den = 0.f;
    float a0 = 0.f, a1 = 0.f, a2 = 0.f, a3 = 0.f, a4 = 0.f, a5 = 0.f;
    if (lane == 0) {
        float z0 = __expf(eloop2[node] - m);
        den = z0;
        float4 lo = ((const float4*)h2pad)[(size_t)node * 2];
        float4 hi = ((const float4*)h2pad)[(size_t)node * 2 + 1];
        a0 = z0 * lo.x; a1 = z0 * lo.y; a2 = z0 * lo.z;
        a3 = z0 * lo.w; a4 = z0 * hi.x; a5 = z0 * hi.y;
    }
    for (int k = rs + lane; k < ke; k += 64) {
        int s = csr[k];
        float4 lo = ((const float4*)h2pad)[(size_t)s * 2];
        float4 hi = ((const float4*)h2pad)[(size_t)s * 2 + 1];
        float z = __expf(lrelu(hi.z + adn) - m);   // hi.z = asrc2[s]
        den += z;
        a0 = fmaf(z, lo.x, a0); a1 = fmaf(z, lo.y, a1); a2 = fmaf(z, lo.z, a2);
        a3 = fmaf(z, lo.w, a3); a4 = fmaf(z, hi.x, a4); a5 = fmaf(z, hi.y, a5);
    }
    #pragma unroll
    for (int mm = 32; mm >= 1; mm >>= 1) {
        den += __shfl_xor(den, mm);
        a0 += __shfl_xor(a0, mm); a1 += __shfl_xor(a1, mm); a2 += __shfl_xor(a2, mm);
        a3 += __shfl_xor(a3, mm); a4 += __shfl_xor(a4, mm); a5 += __shfl_xor(a5, mm);
    }
    if (lane == 0) {
        float inv = 1.f / den;
        float v[6] = { a0 * inv + b2[0], a1 * inv + b2[1], a2 * inv + b2[2],
                       a3 * inv + b2[3], a4 * inv + b2[4], a5 * inv + b2[5] };
        float mxv = -1e30f;
        #pragma unroll
        for (int cc = 0; cc < 6; cc++) mxv = fmaxf(mxv, v[cc]);
        float ssum = 0.f;
        #pragma unroll
        for (int cc = 0; cc < 6; cc++) ssum += __expf(v[cc] - mxv);
        float lse = mxv + logf(ssum);
        #pragma unroll
        for (int cc = 0; cc < 6; cc++) out[node * 6 + cc] = v[cc] - lse;
    }
}

extern "C" void kernel_launch(void* const* d_in, const int* in_sizes, int n_in,
                              void* d_out, int out_size, void* d_ws, size_t ws_size,
                              hipStream_t stream) {
    const float* x      = (const float*)d_in[0];
    const int*   ei     = (const int*)d_in[1];
    const float* W1     = (const float*)d_in[2];
    const float* a_src1 = (const float*)d_in[3];
    const float* a_dst1 = (const float*)d_in[4];
    const float* b1     = (const float*)d_in[5];
    const float* W2     = (const float*)d_in[6];
    const float* a_src2 = (const float*)d_in[7];
    const float* a_dst2 = (const float*)d_in[8];
    const float* b2     = (const float*)d_in[9];
    float* out = (float*)d_out;

    const int N = in_sizes[0] / 7;
    const int E = in_sizes[1] / 2;
    const int* src = ei;
    const int* dst = ei + E;
    const int nbuck = (N + 127) >> 7;

    // Workspace layout
    float* w = (float*)d_ws;
    float* h1     = w;  w += (size_t)N * 64;
    float* asrc1  = w;  w += (size_t)N * 4;
    float* adst1  = w;  w += (size_t)N * 4;
    float* eloop1 = w;  w += (size_t)N * 4;
    float* h2pad  = w;  w += (size_t)N * 8;
    float* asrc2  = w;  w += (size_t)N;
    float* adst2  = w;  w += (size_t)N;
    float* eloop2 = w;  w += (size_t)N;
    // align to 16B for int2
    uintptr_t wp = ((uintptr_t)w + 15) & ~(uintptr_t)15;
    int2* ebuf = (int2*)wp;
    int* ip = (int*)(ebuf + E);
    int* deg      = ip; ip += N;
    int* rowstart = ip; ip += N;
    int* blockSum = ip; ip += 1024;
    int* csr      = ip; ip += E;
    int* bbase    = ip; ip += nbuck + 1;
    int* bcur     = ip; ip += nbuck;
    unsigned* gmax1 = (unsigned*)ip; ip += 4;
    unsigned* gmax2 = (unsigned*)ip; ip += 4;

    const int B = 256;
    dim3 gE((E + B - 1) / B);
    dim3 gScan((N + 255) / 256);
    int nb = (N + 255) / 256;

    initK<<<(N + B - 1) / B, B, 0, stream>>>(deg, gmax1, gmax2, N);
    phaseA<<<dim3((N + 3) / 4), B, 0, stream>>>(x, W1, a_src1, a_dst1, h1, asrc1, adst1, eloop1, N);
    gmax1K<<<128, B, 0, stream>>>(asrc1, gmax1, N);
    degCount<<<gE, B, 0, stream>>>(dst, deg, E);
    scan1<<<gScan, 256, 0, stream>>>(deg, rowstart, blockSum, N);
    scan2<<<1, 1024, 0, stream>>>(blockSum, nb);
    scan3<<<gScan, 256, 0, stream>>>(rowstart, blockSum, N);
    bbaseK<<<(nbuck + 1 + B - 1) / B, B, 0, stream>>>(rowstart, bbase, bcur, nbuck, N, E);
    scatterP1<<<gE, B, 0, stream>>>(src, dst, bbase, bcur, ebuf, E);
    scatterP2<<<dim3(nbuck), B, 0, stream>>>(ebuf, bbase, rowstart, csr);
    gatherL1<<<dim3((N + 15) / 16), B, 0, stream>>>(csr, rowstart, deg, gmax1,
                                                    h1, asrc1, adst1, eloop1,
                                                    b1, W2, a_src2, a_dst2,
                                                    h2pad, asrc2, adst2, eloop2, N);
    gmax2K<<<128, B, 0, stream>>>(asrc2, gmax2, N);
    gatherL2<<<dim3((N + 3) / 4), B, 0, stream>>>(csr, rowstart, deg, gmax2,
                                                  h2pad, adst2, eloop2, b2, out, N);
}

// Round 6
// 510.062 us; speedup vs baseline: 3.9929x; 3.9929x over previous
//
#include <hip/hip_runtime.h>
#include <math.h>

#define NEG_SLOPE 0.2f
__device__ __forceinline__ float lrelu(float x) { return x > 0.f ? x : NEG_SLOPE * x; }

// Order-preserving float<->uint encoding so unsigned atomicMax == float max.
__device__ __forceinline__ unsigned encf(float f) {
    unsigned u = __float_as_uint(f);
    return (u & 0x80000000u) ? ~u : (u | 0x80000000u);
}
__device__ __forceinline__ float decf(unsigned u) {
    return __uint_as_float((u & 0x80000000u) ? (u ^ 0x80000000u) : ~u);
}

__global__ void initK(int* __restrict__ deg, unsigned* __restrict__ gmax1,
                      unsigned* __restrict__ gmax2, int N) {
    int i = blockIdx.x * blockDim.x + threadIdx.x;
    if (i < N) deg[i] = 0;
    if (i < 4) gmax1[i] = 0u;
    if (i == 0) gmax2[0] = 0u;
}

// Phase A: h1 = x @ W1 [N,64]; alpha_src/dst [N,4]; self-loop logit.
__global__ void phaseA(const float* __restrict__ x, const float* __restrict__ W1,
                       const float* __restrict__ a_src, const float* __restrict__ a_dst,
                       float* __restrict__ h1, float* __restrict__ asrc1,
                       float* __restrict__ adst1, float* __restrict__ eloop1, int N) {
    int node = blockIdx.x * 4 + (threadIdx.x >> 6);
    if (node >= N) return;
    int lane = threadIdx.x & 63;
    int head = lane >> 4, c = lane & 15;

    float h = 0.f;
    #pragma unroll
    for (int k = 0; k < 7; k++) h += x[node * 7 + k] * W1[k * 64 + lane];
    h1[node * 64 + lane] = h;

    float s = h * a_src[lane];
    float d = h * a_dst[lane];
    #pragma unroll
    for (int m = 8; m >= 1; m >>= 1) {
        s += __shfl_xor(s, m);
        d += __shfl_xor(d, m);
    }
    if (c == 0) {
        asrc1[node * 4 + head] = s;
        adst1[node * 4 + head] = d;
        eloop1[node * 4 + head] = lrelu(s + d);
    }
}

// Global per-head max of asrc1 [N,4] -> gmax1[4] (encoded).
__global__ void gmax1K(const float* __restrict__ asrc1, unsigned* __restrict__ gmax1, int N) {
    float m0 = -1e30f, m1 = -1e30f, m2 = -1e30f, m3 = -1e30f;
    for (int i = blockIdx.x * blockDim.x + threadIdx.x; i < N; i += gridDim.x * blockDim.x) {
        float4 v = ((const float4*)asrc1)[i];
        m0 = fmaxf(m0, v.x); m1 = fmaxf(m1, v.y);
        m2 = fmaxf(m2, v.z); m3 = fmaxf(m3, v.w);
    }
    #pragma unroll
    for (int mm = 32; mm >= 1; mm >>= 1) {
        m0 = fmaxf(m0, __shfl_xor(m0, mm));
        m1 = fmaxf(m1, __shfl_xor(m1, mm));
        m2 = fmaxf(m2, __shfl_xor(m2, mm));
        m3 = fmaxf(m3, __shfl_xor(m3, mm));
    }
    if ((threadIdx.x & 63) == 0) {
        atomicMax(&gmax1[0], encf(m0));
        atomicMax(&gmax1[1], encf(m1));
        atomicMax(&gmax1[2], encf(m2));
        atomicMax(&gmax1[3], encf(m3));
    }
}

__global__ void gmax2K(const float* __restrict__ asrc2, unsigned* __restrict__ gmax2, int N) {
    float m0 = -1e30f;
    for (int i = blockIdx.x * blockDim.x + threadIdx.x; i < N; i += gridDim.x * blockDim.x)
        m0 = fmaxf(m0, asrc2[i]);
    #pragma unroll
    for (int mm = 32; mm >= 1; mm >>= 1) m0 = fmaxf(m0, __shfl_xor(m0, mm));
    if ((threadIdx.x & 63) == 0) atomicMax(gmax2, encf(m0));
}

__global__ void degCount(const int* __restrict__ dst, int* __restrict__ deg, int E) {
    int i = blockIdx.x * blockDim.x + threadIdx.x;
    if (i < E) atomicAdd(&deg[dst[i]], 1);
}

// Generic exclusive scan, 3 kernels (n up to 262144).
__global__ void scan1(const int* __restrict__ in, int* __restrict__ outv,
                      int* __restrict__ blockSum, int n) {
    __shared__ int sm[256];
    int tid = threadIdx.x;
    int i = blockIdx.x * 256 + tid;
    int v = (i < n) ? in[i] : 0;
    sm[tid] = v;
    __syncthreads();
    for (int off = 1; off < 256; off <<= 1) {
        int t = sm[tid];
        int add = (tid >= off) ? sm[tid - off] : 0;
        __syncthreads();
        sm[tid] = t + add;
        __syncthreads();
    }
    if (i < n) outv[i] = sm[tid] - v;     // exclusive
    if (tid == 255) blockSum[blockIdx.x] = sm[255];
}

__global__ void scan2(int* __restrict__ blockSum, int nb) {
    __shared__ int sm[1024];
    int tid = threadIdx.x;
    int v = (tid < nb) ? blockSum[tid] : 0;
    sm[tid] = v;
    __syncthreads();
    for (int off = 1; off < 1024; off <<= 1) {
        int t = sm[tid];
        int add = (tid >= off) ? sm[tid - off] : 0;
        __syncthreads();
        sm[tid] = t + add;
        __syncthreads();
    }
    if (tid < nb) blockSum[tid] = sm[tid] - v;  // exclusive
}

__global__ void scan3(int* __restrict__ outv, const int* __restrict__ blockSum, int n) {
    int i = blockIdx.x * 256 + threadIdx.x;
    if (i < n) outv[i] += blockSum[blockIdx.x];
}

// --- Block-ordered counting sort of edges into 128-node dst-buckets ---
// histT: per-block LDS histogram of its edge slice; counts[b][i] bucket-major.
__global__ void histT(const int* __restrict__ dst, int* __restrict__ counts,
                      int E, int nbuck) {
    __shared__ int hist[1024];          // nbuck <= 1024 (N <= 131072)
    for (int j = threadIdx.x; j < nbuck; j += blockDim.x) hist[j] = 0;
    __syncthreads();
    int per = (E + gridDim.x - 1) / gridDim.x;
    int i0 = blockIdx.x * per, i1 = min(E, i0 + per);
    for (int i = i0 + threadIdx.x; i < i1; i += blockDim.x)
        atomicAdd(&hist[dst[i] >> 7], 1);
    __syncthreads();
    for (int j = threadIdx.x; j < nbuck; j += blockDim.x)
        counts[j * gridDim.x + blockIdx.x] = hist[j];
}

// scatterS: LDS cursors seeded from scanned offsets; LDS atomics only.
// Each (bucket,block) window (~256B) is written within one block's lifetime.
__global__ void scatterS(const int* __restrict__ src, const int* __restrict__ dst,
                         const int* __restrict__ ocounts, int2* __restrict__ ebuf,
                         int E, int nbuck) {
    __shared__ int cur[1024];
    for (int j = threadIdx.x; j < nbuck; j += blockDim.x)
        cur[j] = ocounts[j * gridDim.x + blockIdx.x];
    __syncthreads();
    int per = (E + gridDim.x - 1) / gridDim.x;
    int i0 = blockIdx.x * per, i1 = min(E, i0 + per);
    for (int i = i0 + threadIdx.x; i < i1; i += blockDim.x) {
        int d = dst[i];
        int pos = atomicAdd(&cur[d >> 7], 1);
        ebuf[pos] = make_int2(src[i], d);
    }
}

// bbase[b] = start of bucket b in ebuf/csr.
__global__ void bbaseK(const int* __restrict__ ocounts, int* __restrict__ bbase,
                       int nbuck, int G, int E) {
    int i = blockIdx.x * blockDim.x + threadIdx.x;
    if (i <= nbuck) bbase[i] = (i < nbuck) ? ocounts[i * G] : E;
}

// Scatter P2: one workgroup per bucket. Coalesced ebuf read, LDS per-node
// cursor, csr writes confined to this bucket's ~16KB window on ONE CU.
__global__ void scatterP2(const int2* __restrict__ ebuf, const int* __restrict__ bbase,
                          const int* __restrict__ rowstart, int* __restrict__ csr) {
    int b = blockIdx.x;
    int beg = bbase[b], end = bbase[b + 1];
    __shared__ int lcur[128];
    if (threadIdx.x < 128) lcur[threadIdx.x] = 0;
    __syncthreads();
    int base = b << 7;
    for (int i = beg + threadIdx.x; i < end; i += blockDim.x) {
        int2 e = ebuf[i];
        int pos = rowstart[e.y] + atomicAdd(&lcur[e.y - base], 1);
        csr[pos] = e.x;
    }
}

// Layer-1 gather: 16 lanes per node (lane t owns channels 4t..4t+3, head=t>>2),
// 4 nodes per wave -> 4 independent gather streams. Single pass (gmax bound).
// Fused epilogue: normalize, +b1, ELU, @W2, layer-2 logits, pack h2pad row.
__global__ void gatherL1(const int* __restrict__ csr, const int* __restrict__ rowstart,
                         const int* __restrict__ deg, const unsigned* __restrict__ gmax1,
                         const float* __restrict__ h1, const float* __restrict__ asrc1,
                         const float* __restrict__ adst1, const float* __restrict__ eloop1,
                         const float* __restrict__ b1, const float* __restrict__ W2,
                         const float* __restrict__ a_src2, const float* __restrict__ a_dst2,
                         float* __restrict__ h2pad, float* __restrict__ asrc2,
                         float* __restrict__ adst2, float* __restrict__ eloop2, int N) {
    int node = blockIdx.x * 16 + (threadIdx.x >> 4);
    if (node >= N) return;
    int t = threadIdx.x & 15;
    int head = t >> 2;

    int rs = rowstart[node], dg = deg[node];
    float adh = adst1[node * 4 + head];
    float el = eloop1[node * 4 + head];
    float m = lrelu(decf(gmax1[head]) + adh);   // upper bound on segment logits

    const float4* h1v = (const float4*)h1;      // h1 as [N][16] of float4
    float z0 = __expf(el - m);
    float den = z0;
    float4 hv0 = h1v[(size_t)node * 16 + t];
    float ax = z0 * hv0.x, ay = z0 * hv0.y, az = z0 * hv0.z, aw = z0 * hv0.w;

    if (dg > 0) {
        int s = csr[rs];
        for (int k = rs; k < rs + dg; ++k) {
            int kk = (k + 1 < rs + dg) ? k + 1 : k;
            int s_next = csr[kk];
            float av = asrc1[s * 4 + head];
            float4 hv = h1v[(size_t)s * 16 + t];
            float z = __expf(lrelu(av + adh) - m);
            den += z;
            ax = fmaf(z, hv.x, ax); ay = fmaf(z, hv.y, ay);
            az = fmaf(z, hv.z, az); aw = fmaf(z, hv.w, aw);
            s = s_next;
        }
    }

    float inv = 1.f / den;
    float4 bv = ((const float4*)b1)[t];
    float v0 = ax * inv + bv.x, v1 = ay * inv + bv.y;
    float v2 = az * inv + bv.z, v3 = aw * inv + bv.w;
    v0 = v0 > 0.f ? v0 : __expf(v0) - 1.f;
    v1 = v1 > 0.f ? v1 : __expf(v1) - 1.f;
    v2 = v2 > 0.f ? v2 : __expf(v2) - 1.f;
    v3 = v3 > 0.f ? v3 : __expf(v3) - 1.f;

    // h2 = v @ W2 (64->6): per-lane partial over 4 channels, reduce over 16 lanes
    float hh[6];
    #pragma unroll
    for (int c2 = 0; c2 < 6; c2++) {
        float p = v0 * W2[(t * 4 + 0) * 6 + c2] + v1 * W2[(t * 4 + 1) * 6 + c2]
                + v2 * W2[(t * 4 + 2) * 6 + c2] + v3 * W2[(t * 4 + 3) * 6 + c2];
        #pragma unroll
        for (int mm = 8; mm >= 1; mm >>= 1) p += __shfl_xor(p, mm);
        hh[c2] = p;
    }
    float as = 0.f, ad = 0.f;
    #pragma unroll
    for (int c2 = 0; c2 < 6; c2++) {
        as += hh[c2] * a_src2[c2];
        ad += hh[c2] * a_dst2[c2];
    }
    if (t == 0) {
        #pragma unroll
        for (int c2 = 0; c2 < 6; c2++) h2pad[(size_t)node * 8 + c2] = hh[c2];
        h2pad[(size_t)node * 8 + 6] = as;   // asrc2 packed into the gather row
        asrc2[node] = as;
        adst2[node] = ad;
        eloop2[node] = lrelu(as + ad);
    }
}

// Layer-2 gather + log_softmax. Wave per node, lane per edge (64 in flight).
// One 32B gather per edge (h2pad row holds h2[0..5] and asrc2).
__global__ void gatherL2(const int* __restrict__ csr, const int* __restrict__ rowstart,
                         const int* __restrict__ deg, const unsigned* __restrict__ gmax2,
                         const float* __restrict__ h2pad, const float* __restrict__ adst2,
                         const float* __restrict__ eloop2,
                         const float* __restrict__ b2, float* __restrict__ out, int N) {
    int node = blockIdx.x * 4 + (threadIdx.x >> 6);
    if (node >= N) return;
    int lane = threadIdx.x & 63;
    int rs = rowstart[node], ke = rs + deg[node];

    float adn = adst2[node];
    float m = lrelu(decf(*gmax2) + adn);

    float den = 0.f;
    float a0 = 0.f, a1 = 0.f, a2 = 0.f, a3 = 0.f, a4 = 0.f, a5 = 0.f;
    if (lane == 0) {
        float z0 = __expf(eloop2[node] - m);
        den = z0;
        float4 lo = ((const float4*)h2pad)[(size_t)node * 2];
        float4 hi = ((const float4*)h2pad)[(size_t)node * 2 + 1];
        a0 = z0 * lo.x; a1 = z0 * lo.y; a2 = z0 * lo.z;
        a3 = z0 * lo.w; a4 = z0 * hi.x; a5 = z0 * hi.y;
    }
    for (int k = rs + lane; k < ke; k += 64) {
        int s = csr[k];
        float4 lo = ((const float4*)h2pad)[(size_t)s * 2];
        float4 hi = ((const float4*)h2pad)[(size_t)s * 2 + 1];
        float z = __expf(lrelu(hi.z + adn) - m);   // hi.z = asrc2[s]
        den += z;
        a0 = fmaf(z, lo.x, a0); a1 = fmaf(z, lo.y, a1); a2 = fmaf(z, lo.z, a2);
        a3 = fmaf(z, lo.w, a3); a4 = fmaf(z, hi.x, a4); a5 = fmaf(z, hi.y, a5);
    }
    #pragma unroll
    for (int mm = 32; mm >= 1; mm >>= 1) {
        den += __shfl_xor(den, mm);
        a0 += __shfl_xor(a0, mm); a1 += __shfl_xor(a1, mm); a2 += __shfl_xor(a2, mm);
        a3 += __shfl_xor(a3, mm); a4 += __shfl_xor(a4, mm); a5 += __shfl_xor(a5, mm);
    }
    if (lane == 0) {
        float inv = 1.f / den;
        float v[6] = { a0 * inv + b2[0], a1 * inv + b2[1], a2 * inv + b2[2],
                       a3 * inv + b2[3], a4 * inv + b2[4], a5 * inv + b2[5] };
        float mxv = -1e30f;
        #pragma unroll
        for (int cc = 0; cc < 6; cc++) mxv = fmaxf(mxv, v[cc]);
        float ssum = 0.f;
        #pragma unroll
        for (int cc = 0; cc < 6; cc++) ssum += __expf(v[cc] - mxv);
        float lse = mxv + logf(ssum);
        #pragma unroll
        for (int cc = 0; cc < 6; cc++) out[node * 6 + cc] = v[cc] - lse;
    }
}

extern "C" void kernel_launch(void* const* d_in, const int* in_sizes, int n_in,
                              void* d_out, int out_size, void* d_ws, size_t ws_size,
                              hipStream_t stream) {
    const float* x      = (const float*)d_in[0];
    const int*   ei     = (const int*)d_in[1];
    const float* W1     = (const float*)d_in[2];
    const float* a_src1 = (const float*)d_in[3];
    const float* a_dst1 = (const float*)d_in[4];
    const float* b1     = (const float*)d_in[5];
    const float* W2     = (const float*)d_in[6];
    const float* a_src2 = (const float*)d_in[7];
    const float* a_dst2 = (const float*)d_in[8];
    const float* b2     = (const float*)d_in[9];
    float* out = (float*)d_out;

    const int N = in_sizes[0] / 7;
    const int E = in_sizes[1] / 2;
    const int* src = ei;
    const int* dst = ei + E;
    const int nbuck = (N + 127) >> 7;
    const int G = 128;                      // sort blocks
    const int M = nbuck * G;                // counts entries

    // Workspace layout
    float* w = (float*)d_ws;
    float* h1     = w;  w += (size_t)N * 64;
    float* asrc1  = w;  w += (size_t)N * 4;
    float* adst1  = w;  w += (size_t)N * 4;
    float* eloop1 = w;  w += (size_t)N * 4;
    float* h2pad  = w;  w += (size_t)N * 8;
    float* asrc2  = w;  w += (size_t)N;
    float* adst2  = w;  w += (size_t)N;
    float* eloop2 = w;  w += (size_t)N;
    uintptr_t wp = ((uintptr_t)w + 15) & ~(uintptr_t)15;
    int2* ebuf = (int2*)wp;
    int* ip = (int*)(ebuf + E);
    int* deg      = ip; ip += N;
    int* rowstart = ip; ip += N;
    int* blockSum = ip; ip += 1024;
    int* csr      = ip; ip += E;
    int* bbase    = ip; ip += nbuck + 1;
    int* counts   = ip; ip += M;
    int* ocounts  = ip; ip += M;
    unsigned* gmax1 = (unsigned*)ip; ip += 4;
    unsigned* gmax2 = (unsigned*)ip; ip += 4;

    const int B = 256;
    dim3 gE((E + B - 1) / B);
    int nbN = (N + 255) / 256;
    int nbM = (M + 255) / 256;

    initK<<<(N + B - 1) / B, B, 0, stream>>>(deg, gmax1, gmax2, N);
    phaseA<<<dim3((N + 3) / 4), B, 0, stream>>>(x, W1, a_src1, a_dst1, h1, asrc1, adst1, eloop1, N);
    gmax1K<<<128, B, 0, stream>>>(asrc1, gmax1, N);
    degCount<<<gE, B, 0, stream>>>(dst, deg, E);
    // node-degree scan -> rowstart
    scan1<<<dim3(nbN), 256, 0, stream>>>(deg, rowstart, blockSum, N);
    scan2<<<1, 1024, 0, stream>>>(blockSum, nbN);
    scan3<<<dim3(nbN), 256, 0, stream>>>(rowstart, blockSum, N);
    // bucket counting sort: hist -> scan -> scatter (no global atomics)
    histT<<<dim3(G), B, 0, stream>>>(dst, counts, E, nbuck);
    scan1<<<dim3(nbM), 256, 0, stream>>>(counts, ocounts, blockSum, M);
    scan2<<<1, 1024, 0, stream>>>(blockSum, nbM);
    scan3<<<dim3(nbM), 256, 0, stream>>>(ocounts, blockSum, M);
    bbaseK<<<(nbuck + 1 + B - 1) / B, B, 0, stream>>>(ocounts, bbase, nbuck, G, E);
    scatterS<<<dim3(G), B, 0, stream>>>(src, dst, ocounts, ebuf, E, nbuck);
    scatterP2<<<dim3(nbuck), B, 0, stream>>>(ebuf, bbase, rowstart, csr);
    // gathers
    gatherL1<<<dim3((N + 15) / 16), B, 0, stream>>>(csr, rowstart, deg, gmax1,
                                                    h1, asrc1, adst1, eloop1,
                                                    b1, W2, a_src2, a_dst2,
                                                    h2pad, asrc2, adst2, eloop2, N);
    gmax2K<<<128, B, 0, stream>>>(asrc2, gmax2, N);
    gatherL2<<<dim3((N + 3) / 4), B, 0, stream>>>(csr, rowstart, deg, gmax2,
                                                  h2pad, adst2, eloop2, b2, out, N);
}

// Round 7
// 345.032 us; speedup vs baseline: 5.9027x; 1.4783x over previous
//
#include <hip/hip_runtime.h>
#include <hip/hip_fp16.h>
#include <math.h>

#define NEG_SLOPE 0.2f
__device__ __forceinline__ float lrelu(float x) { return x > 0.f ? x : NEG_SLOPE * x; }

// Order-preserving float<->uint encoding so unsigned atomicMax == float max.
__device__ __forceinline__ unsigned encf(float f) {
    unsigned u = __float_as_uint(f);
    return (u & 0x80000000u) ? ~u : (u | 0x80000000u);
}
__device__ __forceinline__ float decf(unsigned u) {
    return __uint_as_float((u & 0x80000000u) ? (u ^ 0x80000000u) : ~u);
}

__global__ void initK(unsigned* __restrict__ gmax1, unsigned* __restrict__ gmax2) {
    int i = threadIdx.x;
    if (i < 4) gmax1[i] = 0u;
    if (i == 0) gmax2[0] = 0u;
}

// Phase A: h1 = x @ W1 [N,64] (stored fp16); alpha_src/dst [N,4]; self-loop logit.
__global__ void phaseA(const float* __restrict__ x, const float* __restrict__ W1,
                       const float* __restrict__ a_src, const float* __restrict__ a_dst,
                       __half* __restrict__ h1h, float* __restrict__ asrc1,
                       float* __restrict__ adst1, float* __restrict__ eloop1, int N) {
    int node = blockIdx.x * 4 + (threadIdx.x >> 6);
    if (node >= N) return;
    int lane = threadIdx.x & 63;
    int head = lane >> 4, c = lane & 15;

    float h = 0.f;
    #pragma unroll
    for (int k = 0; k < 7; k++) h += x[node * 7 + k] * W1[k * 64 + lane];

    // pack pairs of channels into half2
    float ho = __shfl_xor(h, 1);
    if (!(lane & 1)) {
        __half2 hp = __floats2half2_rn(h, ho);
        ((__half2*)h1h)[(size_t)node * 32 + (lane >> 1)] = hp;
    }

    float s = h * a_src[lane];
    float d = h * a_dst[lane];
    #pragma unroll
    for (int m = 8; m >= 1; m >>= 1) {
        s += __shfl_xor(s, m);
        d += __shfl_xor(d, m);
    }
    if (c == 0) {
        asrc1[node * 4 + head] = s;
        adst1[node * 4 + head] = d;
        eloop1[node * 4 + head] = lrelu(s + d);
    }
}

// Global per-head max of asrc1 [N,4] -> gmax1[4] (encoded).
__global__ void gmax1K(const float* __restrict__ asrc1, unsigned* __restrict__ gmax1, int N) {
    float m0 = -1e30f, m1 = -1e30f, m2 = -1e30f, m3 = -1e30f;
    for (int i = blockIdx.x * blockDim.x + threadIdx.x; i < N; i += gridDim.x * blockDim.x) {
        float4 v = ((const float4*)asrc1)[i];
        m0 = fmaxf(m0, v.x); m1 = fmaxf(m1, v.y);
        m2 = fmaxf(m2, v.z); m3 = fmaxf(m3, v.w);
    }
    #pragma unroll
    for (int mm = 32; mm >= 1; mm >>= 1) {
        m0 = fmaxf(m0, __shfl_xor(m0, mm));
        m1 = fmaxf(m1, __shfl_xor(m1, mm));
        m2 = fmaxf(m2, __shfl_xor(m2, mm));
        m3 = fmaxf(m3, __shfl_xor(m3, mm));
    }
    if ((threadIdx.x & 63) == 0) {
        atomicMax(&gmax1[0], encf(m0));
        atomicMax(&gmax1[1], encf(m1));
        atomicMax(&gmax1[2], encf(m2));
        atomicMax(&gmax1[3], encf(m3));
    }
}

__global__ void gmax2K(const float* __restrict__ asrc2, unsigned* __restrict__ gmax2, int N) {
    float m0 = -1e30f;
    for (int i = blockIdx.x * blockDim.x + threadIdx.x; i < N; i += gridDim.x * blockDim.x)
        m0 = fmaxf(m0, asrc2[i]);
    #pragma unroll
    for (int mm = 32; mm >= 1; mm >>= 1) m0 = fmaxf(m0, __shfl_xor(m0, mm));
    if ((threadIdx.x & 63) == 0) atomicMax(gmax2, encf(m0));
}

// Generic exclusive scan, 3 kernels (n up to 262144).
__global__ void scan1(const int* __restrict__ in, int* __restrict__ outv,
                      int* __restrict__ blockSum, int n) {
    __shared__ int sm[256];
    int tid = threadIdx.x;
    int i = blockIdx.x * 256 + tid;
    int v = (i < n) ? in[i] : 0;
    sm[tid] = v;
    __syncthreads();
    for (int off = 1; off < 256; off <<= 1) {
        int t = sm[tid];
        int add = (tid >= off) ? sm[tid - off] : 0;
        __syncthreads();
        sm[tid] = t + add;
        __syncthreads();
    }
    if (i < n) outv[i] = sm[tid] - v;     // exclusive
    if (tid == 255) blockSum[blockIdx.x] = sm[255];
}

__global__ void scan2(int* __restrict__ blockSum, int nb) {
    __shared__ int sm[1024];
    int tid = threadIdx.x;
    int v = (tid < nb) ? blockSum[tid] : 0;
    sm[tid] = v;
    __syncthreads();
    for (int off = 1; off < 1024; off <<= 1) {
        int t = sm[tid];
        int add = (tid >= off) ? sm[tid - off] : 0;
        __syncthreads();
        sm[tid] = t + add;
        __syncthreads();
    }
    if (tid < nb) blockSum[tid] = sm[tid] - v;  // exclusive
}

__global__ void scan3(int* __restrict__ outv, const int* __restrict__ blockSum, int n) {
    int i = blockIdx.x * 256 + threadIdx.x;
    if (i < n) outv[i] += blockSum[blockIdx.x];
}

// --- Block-ordered counting sort of edges into 128-node dst-buckets ---
__global__ void histT(const int* __restrict__ dst, int* __restrict__ counts,
                      int E, int nbuck) {
    __shared__ int hist[1024];
    for (int j = threadIdx.x; j < nbuck; j += blockDim.x) hist[j] = 0;
    __syncthreads();
    int per = (E + gridDim.x - 1) / gridDim.x;
    int i0 = blockIdx.x * per, i1 = min(E, i0 + per);
    for (int i = i0 + threadIdx.x; i < i1; i += blockDim.x)
        atomicAdd(&hist[dst[i] >> 7], 1);
    __syncthreads();
    for (int j = threadIdx.x; j < nbuck; j += blockDim.x)
        counts[j * gridDim.x + blockIdx.x] = hist[j];
}

// scatterS: LDS cursors seeded from scanned offsets; LDS atomics only.
__global__ void scatterS(const int* __restrict__ src, const int* __restrict__ dst,
                         const int* __restrict__ ocounts, int2* __restrict__ ebuf,
                         int E, int nbuck) {
    __shared__ int cur[1024];
    for (int j = threadIdx.x; j < nbuck; j += blockDim.x)
        cur[j] = ocounts[j * gridDim.x + blockIdx.x];
    __syncthreads();
    int per = (E + gridDim.x - 1) / gridDim.x;
    int i0 = blockIdx.x * per, i1 = min(E, i0 + per);
    for (int i = i0 + threadIdx.x; i < i1; i += blockDim.x) {
        int d = dst[i];
        int pos = atomicAdd(&cur[d >> 7], 1);
        ebuf[pos] = make_int2(src[i], d);
    }
}

__global__ void bbaseK(const int* __restrict__ ocounts, int* __restrict__ bbase,
                       int nbuck, int G, int E) {
    int i = blockIdx.x * blockDim.x + threadIdx.x;
    if (i <= nbuck) bbase[i] = (i < nbuck) ? ocounts[i * G] : E;
}

// Scatter P2: one workgroup per 128-node bucket.
// Pass 1 counts per-node edges in LDS; in-LDS exclusive scan + bbase gives
// rowstart and deg directly (deletes degCount + node-level scan chain).
// Pass 2 places edges into csr within this bucket's window on ONE CU.
__global__ void scatterP2(const int2* __restrict__ ebuf, const int* __restrict__ bbase,
                          int* __restrict__ rowstart, int* __restrict__ deg,
                          int* __restrict__ csr, int N) {
    int b = blockIdx.x;
    int beg = bbase[b], end = bbase[b + 1];
    int base = b << 7;
    int tid = threadIdx.x;
    __shared__ int cnt[128];
    __shared__ int sc[128];
    __shared__ int rloc[128];
    __shared__ int lcur[128];
    if (tid < 128) cnt[tid] = 0;
    __syncthreads();
    for (int i = beg + tid; i < end; i += blockDim.x)
        atomicAdd(&cnt[ebuf[i].y - base], 1);
    __syncthreads();
    if (tid < 128) sc[tid] = cnt[tid];
    __syncthreads();
    for (int off = 1; off < 128; off <<= 1) {
        int t = (tid < 128) ? sc[tid] : 0;
        int add = (tid >= off && tid < 128) ? sc[tid - off] : 0;
        __syncthreads();
        if (tid < 128) sc[tid] = t + add;
        __syncthreads();
    }
    if (tid < 128) {
        int rs = beg + sc[tid] - cnt[tid];   // exclusive scan + bucket base
        rloc[tid] = rs;
        lcur[tid] = 0;
        int node = base + tid;
        if (node < N) { rowstart[node] = rs; deg[node] = cnt[tid]; }
    }
    __syncthreads();
    for (int i = beg + tid; i < end; i += blockDim.x) {
        int2 e = ebuf[i];
        int j = e.y - base;
        int pos = rloc[j] + atomicAdd(&lcur[j], 1);
        csr[pos] = e.x;
    }
}

// Layer-1 gather: 16 lanes per node (lane t owns channels 4t..4t+3, head=t>>2),
// 4 nodes per wave. fp16 h1 rows (128B/edge), value-prefetch pipeline.
// Fused epilogue: normalize, +b1, ELU, @W2, layer-2 logits, pack h2pad row.
__global__ void gatherL1(const int* __restrict__ csr, const int* __restrict__ rowstart,
                         const int* __restrict__ deg, const unsigned* __restrict__ gmax1,
                         const __half* __restrict__ h1h, const float* __restrict__ asrc1,
                         const float* __restrict__ adst1, const float* __restrict__ eloop1,
                         const float* __restrict__ b1, const float* __restrict__ W2,
                         const float* __restrict__ a_src2, const float* __restrict__ a_dst2,
                         float* __restrict__ h2pad, float* __restrict__ asrc2,
                         float* __restrict__ adst2, float* __restrict__ eloop2, int N) {
    int node = blockIdx.x * 16 + (threadIdx.x >> 4);
    if (node >= N) return;
    int t = threadIdx.x & 15;
    int head = t >> 2;

    int rs = rowstart[node], dg = deg[node];
    float adh = adst1[node * 4 + head];
    float el = eloop1[node * 4 + head];
    float m = lrelu(decf(gmax1[head]) + adh);   // upper bound on segment logits

    const uint2* h1v = (const uint2*)h1h;       // row = 16 uint2 (128B)
    float z0 = __expf(el - m);
    float den = z0;
    uint2 hv0 = h1v[(size_t)node * 16 + t];
    float2 f0 = __half22float2(*(const __half2*)&hv0.x);
    float2 f1 = __half22float2(*(const __half2*)&hv0.y);
    float ax = z0 * f0.x, ay = z0 * f0.y, az = z0 * f1.x, aw = z0 * f1.y;

    if (dg > 0) {
        int ke = rs + dg;
        int s = csr[rs];
        float av = asrc1[s * 4 + head];
        uint2 hr = h1v[(size_t)s * 16 + t];
        for (int k = rs; k < ke; ++k) {
            int kk = (k + 1 < ke) ? k + 1 : k;
            int s2 = csr[kk];
            float av2 = asrc1[s2 * 4 + head];
            uint2 hr2 = h1v[(size_t)s2 * 16 + t];
            float z = __expf(lrelu(av + adh) - m);
            den += z;
            float2 g0 = __half22float2(*(const __half2*)&hr.x);
            float2 g1 = __half22float2(*(const __half2*)&hr.y);
            ax = fmaf(z, g0.x, ax); ay = fmaf(z, g0.y, ay);
            az = fmaf(z, g1.x, az); aw = fmaf(z, g1.y, aw);
            av = av2; hr = hr2;
        }
    }

    float inv = 1.f / den;
    float4 bv = ((const float4*)b1)[t];
    float v0 = ax * inv + bv.x, v1 = ay * inv + bv.y;
    float v2 = az * inv + bv.z, v3 = aw * inv + bv.w;
    v0 = v0 > 0.f ? v0 : __expf(v0) - 1.f;
    v1 = v1 > 0.f ? v1 : __expf(v1) - 1.f;
    v2 = v2 > 0.f ? v2 : __expf(v2) - 1.f;
    v3 = v3 > 0.f ? v3 : __expf(v3) - 1.f;

    // h2 = v @ W2 (64->6): per-lane partial over 4 channels, reduce over 16 lanes
    float hh[6];
    #pragma unroll
    for (int c2 = 0; c2 < 6; c2++) {
        float p = v0 * W2[(t * 4 + 0) * 6 + c2] + v1 * W2[(t * 4 + 1) * 6 + c2]
                + v2 * W2[(t * 4 + 2) * 6 + c2] + v3 * W2[(t * 4 + 3) * 6 + c2];
        #pragma unroll
        for (int mm = 8; mm >= 1; mm >>= 1) p += __shfl_xor(p, mm);
        hh[c2] = p;
    }
    float as = 0.f, ad = 0.f;
    #pragma unroll
    for (int c2 = 0; c2 < 6; c2++) {
        as += hh[c2] * a_src2[c2];
        ad += hh[c2] * a_dst2[c2];
    }
    if (t == 0) {
        #pragma unroll
        for (int c2 = 0; c2 < 6; c2++) h2pad[(size_t)node * 8 + c2] = hh[c2];
        h2pad[(size_t)node * 8 + 6] = as;   // asrc2 packed into the gather row
        asrc2[node] = as;
        adst2[node] = ad;
        eloop2[node] = lrelu(as + ad);
    }
}

// Layer-2 gather + log_softmax. Wave per node, lane per edge (64 in flight).
__global__ void gatherL2(const int* __restrict__ csr, const int* __restrict__ rowstart,
                         const int* __restrict__ deg, const unsigned* __restrict__ gmax2,
                         const float* __restrict__ h2pad, const float* __restrict__ adst2,
                         const float* __restrict__ eloop2,
                         const float* __restrict__ b2, float* __restrict__ out, int N) {
    int node = blockIdx.x * 4 + (threadIdx.x >> 6);
    if (node >= N) return;
    int lane = threadIdx.x & 63;
    int rs = rowstart[node], ke = rs + deg[node];

    float adn = adst2[node];
    float m = lrelu(decf(*gmax2) + adn);

    float den = 0.f;
    float a0 = 0.f, a1 = 0.f, a2 = 0.f, a3 = 0.f, a4 = 0.f, a5 = 0.f;
    if (lane == 0) {
        float z0 = __expf(eloop2[node] - m);
        den = z0;
        float4 lo = ((const float4*)h2pad)[(size_t)node * 2];
        float4 hi = ((const float4*)h2pad)[(size_t)node * 2 + 1];
        a0 = z0 * lo.x; a1 = z0 * lo.y; a2 = z0 * lo.z;
        a3 = z0 * lo.w; a4 = z0 * hi.x; a5 = z0 * hi.y;
    }
    for (int k = rs + lane; k < ke; k += 64) {
        int s = csr[k];
        float4 lo = ((const float4*)h2pad)[(size_t)s * 2];
        float4 hi = ((const float4*)h2pad)[(size_t)s * 2 + 1];
        float z = __expf(lrelu(hi.z + adn) - m);   // hi.z = asrc2[s]
        den += z;
        a0 = fmaf(z, lo.x, a0); a1 = fmaf(z, lo.y, a1); a2 = fmaf(z, lo.z, a2);
        a3 = fmaf(z, lo.w, a3); a4 = fmaf(z, hi.x, a4); a5 = fmaf(z, hi.y, a5);
    }
    #pragma unroll
    for (int mm = 32; mm >= 1; mm >>= 1) {
        den += __shfl_xor(den, mm);
        a0 += __shfl_xor(a0, mm); a1 += __shfl_xor(a1, mm); a2 += __shfl_xor(a2, mm);
        a3 += __shfl_xor(a3, mm); a4 += __shfl_xor(a4, mm); a5 += __shfl_xor(a5, mm);
    }
    if (lane == 0) {
        float inv = 1.f / den;
        float v[6] = { a0 * inv + b2[0], a1 * inv + b2[1], a2 * inv + b2[2],
                       a3 * inv + b2[3], a4 * inv + b2[4], a5 * inv + b2[5] };
        float mxv = -1e30f;
        #pragma unroll
        for (int cc = 0; cc < 6; cc++) mxv = fmaxf(mxv, v[cc]);
        float ssum = 0.f;
        #pragma unroll
        for (int cc = 0; cc < 6; cc++) ssum += __expf(v[cc] - mxv);
        float lse = mxv + logf(ssum);
        #pragma unroll
        for (int cc = 0; cc < 6; cc++) out[node * 6 + cc] = v[cc] - lse;
    }
}

extern "C" void kernel_launch(void* const* d_in, const int* in_sizes, int n_in,
                              void* d_out, int out_size, void* d_ws, size_t ws_size,
                              hipStream_t stream) {
    const float* x      = (const float*)d_in[0];
    const int*   ei     = (const int*)d_in[1];
    const float* W1     = (const float*)d_in[2];
    const float* a_src1 = (const float*)d_in[3];
    const float* a_dst1 = (const float*)d_in[4];
    const float* b1     = (const float*)d_in[5];
    const float* W2     = (const float*)d_in[6];
    const float* a_src2 = (const float*)d_in[7];
    const float* a_dst2 = (const float*)d_in[8];
    const float* b2     = (const float*)d_in[9];
    float* out = (float*)d_out;

    const int N = in_sizes[0] / 7;
    const int E = in_sizes[1] / 2;
    const int* src = ei;
    const int* dst = ei + E;
    const int nbuck = (N + 127) >> 7;
    const int G = 128;                      // sort blocks
    const int M = nbuck * G;                // counts entries

    // Workspace layout
    float* w = (float*)d_ws;
    __half* h1h  = (__half*)w;  w += (size_t)N * 32;   // N*64 halves
    float* asrc1  = w;  w += (size_t)N * 4;
    float* adst1  = w;  w += (size_t)N * 4;
    float* eloop1 = w;  w += (size_t)N * 4;
    float* h2pad  = w;  w += (size_t)N * 8;
    float* asrc2  = w;  w += (size_t)N;
    float* adst2  = w;  w += (size_t)N;
    float* eloop2 = w;  w += (size_t)N;
    uintptr_t wp = ((uintptr_t)w + 15) & ~(uintptr_t)15;
    int2* ebuf = (int2*)wp;
    int* ip = (int*)(ebuf + E);
    int* deg      = ip; ip += N;
    int* rowstart = ip; ip += N;
    int* blockSum = ip; ip += 1024;
    int* csr      = ip; ip += E;
    int* bbase    = ip; ip += nbuck + 1;
    int* counts   = ip; ip += M;
    int* ocounts  = ip; ip += M;
    unsigned* gmax1 = (unsigned*)ip; ip += 4;
    unsigned* gmax2 = (unsigned*)ip; ip += 4;

    const int B = 256;
    int nbM = (M + 255) / 256;

    initK<<<1, 64, 0, stream>>>(gmax1, gmax2);
    phaseA<<<dim3((N + 3) / 4), B, 0, stream>>>(x, W1, a_src1, a_dst1, h1h, asrc1, adst1, eloop1, N);
    gmax1K<<<128, B, 0, stream>>>(asrc1, gmax1, N);
    // bucket counting sort: hist -> scan -> scatter (no global atomics)
    histT<<<dim3(G), B, 0, stream>>>(dst, counts, E, nbuck);
    scan1<<<dim3(nbM), 256, 0, stream>>>(counts, ocounts, blockSum, M);
    scan2<<<1, 1024, 0, stream>>>(blockSum, nbM);
    scan3<<<dim3(nbM), 256, 0, stream>>>(ocounts, blockSum, M);
    bbaseK<<<(nbuck + 1 + B - 1) / B, B, 0, stream>>>(ocounts, bbase, nbuck, G, E);
    scatterS<<<dim3(G), B, 0, stream>>>(src, dst, ocounts, ebuf, E, nbuck);
    scatterP2<<<dim3(nbuck), B, 0, stream>>>(ebuf, bbase, rowstart, deg, csr, N);
    // gathers
    gatherL1<<<dim3((N + 15) / 16), B, 0, stream>>>(csr, rowstart, deg, gmax1,
                                                    h1h, asrc1, adst1, eloop1,
                                                    b1, W2, a_src2, a_dst2,
                                                    h2pad, asrc2, adst2, eloop2, N);
    gmax2K<<<128, B, 0, stream>>>(asrc2, gmax2, N);
    gatherL2<<<dim3((N + 3) / 4), B, 0, stream>>>(csr, rowstart, deg, gmax2,
                                                  h2pad, adst2, eloop2, b2, out, N);
}

// Round 8
// 319.313 us; speedup vs baseline: 6.3781x; 1.0805x over previous
//
#include <hip/hip_runtime.h>
#include <hip/hip_fp16.h>
#include <math.h>

#define NEG_SLOPE 0.2f
__device__ __forceinline__ float lrelu(float x) { return x > 0.f ? x : NEG_SLOPE * x; }

// Order-preserving float<->uint encoding so unsigned atomicMax == float max.
__device__ __forceinline__ unsigned encf(float f) {
    unsigned u = __float_as_uint(f);
    return (u & 0x80000000u) ? ~u : (u | 0x80000000u);
}
__device__ __forceinline__ float decf(unsigned u) {
    return __uint_as_float((u & 0x80000000u) ? (u ^ 0x80000000u) : ~u);
}

// Phase A: h1 = x @ W1 [N,64] (stored fp16); alpha_src/dst [N,4]; self-loop logit.
// Block 0 also zeroes the gmax accumulators (replaces initK).
__global__ void phaseA(const float* __restrict__ x, const float* __restrict__ W1,
                       const float* __restrict__ a_src, const float* __restrict__ a_dst,
                       __half* __restrict__ h1h, float* __restrict__ asrc1,
                       float* __restrict__ adst1, float* __restrict__ eloop1,
                       unsigned* __restrict__ gmax1, unsigned* __restrict__ gmax2, int N) {
    if (blockIdx.x == 0 && threadIdx.x < 5) {
        if (threadIdx.x < 4) gmax1[threadIdx.x] = 0u;
        else gmax2[0] = 0u;
    }
    int node = blockIdx.x * 4 + (threadIdx.x >> 6);
    if (node >= N) return;
    int lane = threadIdx.x & 63;
    int head = lane >> 4, c = lane & 15;

    float h = 0.f;
    #pragma unroll
    for (int k = 0; k < 7; k++) h += x[node * 7 + k] * W1[k * 64 + lane];

    // pack pairs of channels into half2
    float ho = __shfl_xor(h, 1);
    if (!(lane & 1)) {
        __half2 hp = __floats2half2_rn(h, ho);
        ((__half2*)h1h)[(size_t)node * 32 + (lane >> 1)] = hp;
    }

    float s = h * a_src[lane];
    float d = h * a_dst[lane];
    #pragma unroll
    for (int m = 8; m >= 1; m >>= 1) {
        s += __shfl_xor(s, m);
        d += __shfl_xor(d, m);
    }
    if (c == 0) {
        asrc1[node * 4 + head] = s;
        adst1[node * 4 + head] = d;
        eloop1[node * 4 + head] = lrelu(s + d);
    }
}

// Global per-head max of asrc1 [N,4] -> gmax1[4] (encoded).
__global__ void gmax1K(const float* __restrict__ asrc1, unsigned* __restrict__ gmax1, int N) {
    float m0 = -1e30f, m1 = -1e30f, m2 = -1e30f, m3 = -1e30f;
    for (int i = blockIdx.x * blockDim.x + threadIdx.x; i < N; i += gridDim.x * blockDim.x) {
        float4 v = ((const float4*)asrc1)[i];
        m0 = fmaxf(m0, v.x); m1 = fmaxf(m1, v.y);
        m2 = fmaxf(m2, v.z); m3 = fmaxf(m3, v.w);
    }
    #pragma unroll
    for (int mm = 32; mm >= 1; mm >>= 1) {
        m0 = fmaxf(m0, __shfl_xor(m0, mm));
        m1 = fmaxf(m1, __shfl_xor(m1, mm));
        m2 = fmaxf(m2, __shfl_xor(m2, mm));
        m3 = fmaxf(m3, __shfl_xor(m3, mm));
    }
    if ((threadIdx.x & 63) == 0) {
        atomicMax(&gmax1[0], encf(m0));
        atomicMax(&gmax1[1], encf(m1));
        atomicMax(&gmax1[2], encf(m2));
        atomicMax(&gmax1[3], encf(m3));
    }
}

__global__ void gmax2K(const float* __restrict__ asrc2, unsigned* __restrict__ gmax2, int N) {
    float m0 = -1e30f;
    for (int i = blockIdx.x * blockDim.x + threadIdx.x; i < N; i += gridDim.x * blockDim.x)
        m0 = fmaxf(m0, asrc2[i]);
    #pragma unroll
    for (int mm = 32; mm >= 1; mm >>= 1) m0 = fmaxf(m0, __shfl_xor(m0, mm));
    if ((threadIdx.x & 63) == 0) atomicMax(gmax2, encf(m0));
}

// Generic exclusive scan, 3 kernels (n up to 262144).
__global__ void scan1(const int* __restrict__ in, int* __restrict__ outv,
                      int* __restrict__ blockSum, int n) {
    __shared__ int sm[256];
    int tid = threadIdx.x;
    int i = blockIdx.x * 256 + tid;
    int v = (i < n) ? in[i] : 0;
    sm[tid] = v;
    __syncthreads();
    for (int off = 1; off < 256; off <<= 1) {
        int t = sm[tid];
        int add = (tid >= off) ? sm[tid - off] : 0;
        __syncthreads();
        sm[tid] = t + add;
        __syncthreads();
    }
    if (i < n) outv[i] = sm[tid] - v;     // exclusive
    if (tid == 255) blockSum[blockIdx.x] = sm[255];
}

__global__ void scan2(int* __restrict__ blockSum, int nb) {
    __shared__ int sm[1024];
    int tid = threadIdx.x;
    int v = (tid < nb) ? blockSum[tid] : 0;
    sm[tid] = v;
    __syncthreads();
    for (int off = 1; off < 1024; off <<= 1) {
        int t = sm[tid];
        int add = (tid >= off) ? sm[tid - off] : 0;
        __syncthreads();
        sm[tid] = t + add;
        __syncthreads();
    }
    if (tid < nb) blockSum[tid] = sm[tid] - v;  // exclusive
}

__global__ void scan3(int* __restrict__ outv, const int* __restrict__ blockSum, int n) {
    int i = blockIdx.x * 256 + threadIdx.x;
    if (i < n) outv[i] += blockSum[blockIdx.x];
}

// --- Block-ordered counting sort of edges into 128-node dst-buckets ---
__global__ void histT(const int* __restrict__ dst, int* __restrict__ counts,
                      int E, int nbuck) {
    __shared__ int hist[1024];
    for (int j = threadIdx.x; j < nbuck; j += blockDim.x) hist[j] = 0;
    __syncthreads();
    int per = (E + gridDim.x - 1) / gridDim.x;
    int i0 = blockIdx.x * per, i1 = min(E, i0 + per);
    for (int i = i0 + threadIdx.x; i < i1; i += blockDim.x)
        atomicAdd(&hist[dst[i] >> 7], 1);
    __syncthreads();
    for (int j = threadIdx.x; j < nbuck; j += blockDim.x)
        counts[j * gridDim.x + blockIdx.x] = hist[j];
}

// scatterS: LDS cursors seeded from scanned offsets; LDS atomics only.
__global__ void scatterS(const int* __restrict__ src, const int* __restrict__ dst,
                         const int* __restrict__ ocounts, int2* __restrict__ ebuf,
                         int E, int nbuck) {
    __shared__ int cur[1024];
    for (int j = threadIdx.x; j < nbuck; j += blockDim.x)
        cur[j] = ocounts[j * gridDim.x + blockIdx.x];
    __syncthreads();
    int per = (E + gridDim.x - 1) / gridDim.x;
    int i0 = blockIdx.x * per, i1 = min(E, i0 + per);
    for (int i = i0 + threadIdx.x; i < i1; i += blockDim.x) {
        int d = dst[i];
        int pos = atomicAdd(&cur[d >> 7], 1);
        ebuf[pos] = make_int2(src[i], d);
    }
}

// Scatter P2: one workgroup per 128-node bucket. Bucket bases read straight
// from ocounts (bbaseK folded in). Pass 1 counts per-node edges in LDS;
// in-LDS scan gives rowstart/deg; pass 2 places edges into csr on ONE CU.
__global__ void scatterP2(const int2* __restrict__ ebuf, const int* __restrict__ ocounts,
                          int* __restrict__ rowstart, int* __restrict__ deg,
                          int* __restrict__ csr, int N, int E, int G, int nbuck) {
    int b = blockIdx.x;
    int beg = ocounts[b * G];
    int end = (b + 1 < nbuck) ? ocounts[(b + 1) * G] : E;
    int base = b << 7;
    int tid = threadIdx.x;
    __shared__ int cnt[128];
    __shared__ int sc[128];
    __shared__ int rloc[128];
    __shared__ int lcur[128];
    if (tid < 128) cnt[tid] = 0;
    __syncthreads();
    for (int i = beg + tid; i < end; i += blockDim.x)
        atomicAdd(&cnt[ebuf[i].y - base], 1);
    __syncthreads();
    if (tid < 128) sc[tid] = cnt[tid];
    __syncthreads();
    for (int off = 1; off < 128; off <<= 1) {
        int t = (tid < 128) ? sc[tid] : 0;
        int add = (tid >= off && tid < 128) ? sc[tid - off] : 0;
        __syncthreads();
        if (tid < 128) sc[tid] = t + add;
        __syncthreads();
    }
    if (tid < 128) {
        int rs = beg + sc[tid] - cnt[tid];   // exclusive scan + bucket base
        rloc[tid] = rs;
        lcur[tid] = 0;
        int node = base + tid;
        if (node < N) { rowstart[node] = rs; deg[node] = cnt[tid]; }
    }
    __syncthreads();
    for (int i = beg + tid; i < end; i += blockDim.x) {
        int2 e = ebuf[i];
        int j = e.y - base;
        int pos = rloc[j] + atomicAdd(&lcur[j], 1);
        csr[pos] = e.x;
    }
}

// Layer-1 gather: 8 lanes per node (lane t owns channels 8t..8t+7, head=t>>1),
// 8 nodes per wave -> 8 independent gather streams, depth-2 value prefetch.
// Fused epilogue: normalize, +b1, ELU, @W2, layer-2 logits, pack h2pad row.
__global__ void gatherL1(const int* __restrict__ csr, const int* __restrict__ rowstart,
                         const int* __restrict__ deg, const unsigned* __restrict__ gmax1,
                         const __half* __restrict__ h1h, const float* __restrict__ asrc1,
                         const float* __restrict__ adst1, const float* __restrict__ eloop1,
                         const float* __restrict__ b1, const float* __restrict__ W2,
                         const float* __restrict__ a_src2, const float* __restrict__ a_dst2,
                         float* __restrict__ h2pad, float* __restrict__ asrc2,
                         float* __restrict__ adst2, float* __restrict__ eloop2, int N) {
    int node = blockIdx.x * 32 + (threadIdx.x >> 3);
    if (node >= N) return;
    int t = threadIdx.x & 7;
    int head = t >> 1;

    int rs = rowstart[node], dg = deg[node];
    float adh = adst1[node * 4 + head];
    float el = eloop1[node * 4 + head];
    float m = lrelu(decf(gmax1[head]) + adh);   // upper bound on segment logits

    const uint4* h1v = (const uint4*)h1h;       // row = 8 uint4 (128B)
    float z0 = __expf(el - m);
    float den = z0;
    uint4 hv0 = h1v[(size_t)node * 8 + t];
    float2 f0 = __half22float2(*(const __half2*)&hv0.x);
    float2 f1 = __half22float2(*(const __half2*)&hv0.y);
    float2 f2 = __half22float2(*(const __half2*)&hv0.z);
    float2 f3 = __half22float2(*(const __half2*)&hv0.w);
    float a0 = z0 * f0.x, a1 = z0 * f0.y, a2 = z0 * f1.x, a3 = z0 * f1.y;
    float a4 = z0 * f2.x, a5 = z0 * f2.y, a6 = z0 * f3.x, a7 = z0 * f3.y;

    if (dg > 0) {
        int ke = rs + dg;
        int s = csr[rs];
        float av = asrc1[s * 4 + head];
        uint4 hr = h1v[(size_t)s * 8 + t];
        for (int k = rs; k < ke; ++k) {
            int kk = (k + 1 < ke) ? k + 1 : k;
            int s2 = csr[kk];
            float av2 = asrc1[s2 * 4 + head];
            uint4 hr2 = h1v[(size_t)s2 * 8 + t];
            float z = __expf(lrelu(av + adh) - m);
            den += z;
            float2 g0 = __half22float2(*(const __half2*)&hr.x);
            float2 g1 = __half22float2(*(const __half2*)&hr.y);
            float2 g2 = __half22float2(*(const __half2*)&hr.z);
            float2 g3 = __half22float2(*(const __half2*)&hr.w);
            a0 = fmaf(z, g0.x, a0); a1 = fmaf(z, g0.y, a1);
            a2 = fmaf(z, g1.x, a2); a3 = fmaf(z, g1.y, a3);
            a4 = fmaf(z, g2.x, a4); a5 = fmaf(z, g2.y, a5);
            a6 = fmaf(z, g3.x, a6); a7 = fmaf(z, g3.y, a7);
            av = av2; hr = hr2;
        }
    }

    float inv = 1.f / den;
    const float4* b1v = (const float4*)b1;
    float4 bA = b1v[t * 2], bB = b1v[t * 2 + 1];
    float v0 = a0 * inv + bA.x, v1 = a1 * inv + bA.y;
    float v2 = a2 * inv + bA.z, v3 = a3 * inv + bA.w;
    float v4 = a4 * inv + bB.x, v5 = a5 * inv + bB.y;
    float v6 = a6 * inv + bB.z, v7 = a7 * inv + bB.w;
    v0 = v0 > 0.f ? v0 : __expf(v0) - 1.f;
    v1 = v1 > 0.f ? v1 : __expf(v1) - 1.f;
    v2 = v2 > 0.f ? v2 : __expf(v2) - 1.f;
    v3 = v3 > 0.f ? v3 : __expf(v3) - 1.f;
    v4 = v4 > 0.f ? v4 : __expf(v4) - 1.f;
    v5 = v5 > 0.f ? v5 : __expf(v5) - 1.f;
    v6 = v6 > 0.f ? v6 : __expf(v6) - 1.f;
    v7 = v7 > 0.f ? v7 : __expf(v7) - 1.f;

    // h2 = v @ W2 (64->6): per-lane partial over 8 channels, reduce over 8 lanes
    float hh[6];
    #pragma unroll
    for (int c2 = 0; c2 < 6; c2++) {
        const float* Wc = &W2[(t * 8) * 6 + c2];
        float p = v0 * Wc[0] + v1 * Wc[6] + v2 * Wc[12] + v3 * Wc[18]
                + v4 * Wc[24] + v5 * Wc[30] + v6 * Wc[36] + v7 * Wc[42];
        #pragma unroll
        for (int mm = 4; mm >= 1; mm >>= 1) p += __shfl_xor(p, mm);
        hh[c2] = p;
    }
    float as = 0.f, ad = 0.f;
    #pragma unroll
    for (int c2 = 0; c2 < 6; c2++) {
        as += hh[c2] * a_src2[c2];
        ad += hh[c2] * a_dst2[c2];
    }
    if (t == 0) {
        #pragma unroll
        for (int c2 = 0; c2 < 6; c2++) h2pad[(size_t)node * 8 + c2] = hh[c2];
        h2pad[(size_t)node * 8 + 6] = as;   // asrc2 packed into the gather row
        asrc2[node] = as;
        adst2[node] = ad;
        eloop2[node] = lrelu(as + ad);
    }
}

// Layer-2 gather + log_softmax. Wave per node, lane per edge (64 in flight).
__global__ void gatherL2(const int* __restrict__ csr, const int* __restrict__ rowstart,
                         const int* __restrict__ deg, const unsigned* __restrict__ gmax2,
                         const float* __restrict__ h2pad, const float* __restrict__ adst2,
                         const float* __restrict__ eloop2,
                         const float* __restrict__ b2, float* __restrict__ out, int N) {
    int node = blockIdx.x * 4 + (threadIdx.x >> 6);
    if (node >= N) return;
    int lane = threadIdx.x & 63;
    int rs = rowstart[node], ke = rs + deg[node];

    float adn = adst2[node];
    float m = lrelu(decf(*gmax2) + adn);

    float den = 0.f;
    float a0 = 0.f, a1 = 0.f, a2 = 0.f, a3 = 0.f, a4 = 0.f, a5 = 0.f;
    if (lane == 0) {
        float z0 = __expf(eloop2[node] - m);
        den = z0;
        float4 lo = ((const float4*)h2pad)[(size_t)node * 2];
        float4 hi = ((const float4*)h2pad)[(size_t)node * 2 + 1];
        a0 = z0 * lo.x; a1 = z0 * lo.y; a2 = z0 * lo.z;
        a3 = z0 * lo.w; a4 = z0 * hi.x; a5 = z0 * hi.y;
    }
    for (int k = rs + lane; k < ke; k += 64) {
        int s = csr[k];
        float4 lo = ((const float4*)h2pad)[(size_t)s * 2];
        float4 hi = ((const float4*)h2pad)[(size_t)s * 2 + 1];
        float z = __expf(lrelu(hi.z + adn) - m);   // hi.z = asrc2[s]
        den += z;
        a0 = fmaf(z, lo.x, a0); a1 = fmaf(z, lo.y, a1); a2 = fmaf(z, lo.z, a2);
        a3 = fmaf(z, lo.w, a3); a4 = fmaf(z, hi.x, a4); a5 = fmaf(z, hi.y, a5);
    }
    #pragma unroll
    for (int mm = 32; mm >= 1; mm >>= 1) {
        den += __shfl_xor(den, mm);
        a0 += __shfl_xor(a0, mm); a1 += __shfl_xor(a1, mm); a2 += __shfl_xor(a2, mm);
        a3 += __shfl_xor(a3, mm); a4 += __shfl_xor(a4, mm); a5 += __shfl_xor(a5, mm);
    }
    if (lane == 0) {
        float inv = 1.f / den;
        float v[6] = { a0 * inv + b2[0], a1 * inv + b2[1], a2 * inv + b2[2],
                       a3 * inv + b2[3], a4 * inv + b2[4], a5 * inv + b2[5] };
        float mxv = -1e30f;
        #pragma unroll
        for (int cc = 0; cc < 6; cc++) mxv = fmaxf(mxv, v[cc]);
        float ssum = 0.f;
        #pragma unroll
        for (int cc = 0; cc < 6; cc++) ssum += __expf(v[cc] - mxv);
        float lse = mxv + logf(ssum);
        #pragma unroll
        for (int cc = 0; cc < 6; cc++) out[node * 6 + cc] = v[cc] - lse;
    }
}

extern "C" void kernel_launch(void* const* d_in, const int* in_sizes, int n_in,
                              void* d_out, int out_size, void* d_ws, size_t ws_size,
                              hipStream_t stream) {
    const float* x      = (const float*)d_in[0];
    const int*   ei     = (const int*)d_in[1];
    const float* W1     = (const float*)d_in[2];
    const float* a_src1 = (const float*)d_in[3];
    const float* a_dst1 = (const float*)d_in[4];
    const float* b1     = (const float*)d_in[5];
    const float* W2     = (const float*)d_in[6];
    const float* a_src2 = (const float*)d_in[7];
    const float* a_dst2 = (const float*)d_in[8];
    const float* b2     = (const float*)d_in[9];
    float* out = (float*)d_out;

    const int N = in_sizes[0] / 7;
    const int E = in_sizes[1] / 2;
    const int* src = ei;
    const int* dst = ei + E;
    const int nbuck = (N + 127) >> 7;
    const int G = 128;                      // sort blocks
    const int M = nbuck * G;                // counts entries

    // Workspace layout
    float* w = (float*)d_ws;
    __half* h1h  = (__half*)w;  w += (size_t)N * 32;   // N*64 halves
    float* asrc1  = w;  w += (size_t)N * 4;
    float* adst1  = w;  w += (size_t)N * 4;
    float* eloop1 = w;  w += (size_t)N * 4;
    float* h2pad  = w;  w += (size_t)N * 8;
    float* asrc2  = w;  w += (size_t)N;
    float* adst2  = w;  w += (size_t)N;
    float* eloop2 = w;  w += (size_t)N;
    uintptr_t wp = ((uintptr_t)w + 15) & ~(uintptr_t)15;
    int2* ebuf = (int2*)wp;
    int* ip = (int*)(ebuf + E);
    int* deg      = ip; ip += N;
    int* rowstart = ip; ip += N;
    int* blockSum = ip; ip += 1024;
    int* csr      = ip; ip += E;
    int* counts   = ip; ip += M;
    int* ocounts  = ip; ip += M;
    unsigned* gmax1 = (unsigned*)ip; ip += 4;
    unsigned* gmax2 = (unsigned*)ip; ip += 4;

    const int B = 256;
    int nbM = (M + 255) / 256;

    phaseA<<<dim3((N + 3) / 4), B, 0, stream>>>(x, W1, a_src1, a_dst1, h1h, asrc1,
                                                adst1, eloop1, gmax1, gmax2, N);
    gmax1K<<<128, B, 0, stream>>>(asrc1, gmax1, N);
    // bucket counting sort: hist -> scan -> scatter (no global atomics)
    histT<<<dim3(G), B, 0, stream>>>(dst, counts, E, nbuck);
    scan1<<<dim3(nbM), 256, 0, stream>>>(counts, ocounts, blockSum, M);
    scan2<<<1, 1024, 0, stream>>>(blockSum, nbM);
    scan3<<<dim3(nbM), 256, 0, stream>>>(ocounts, blockSum, M);
    scatterS<<<dim3(G), B, 0, stream>>>(src, dst, ocounts, ebuf, E, nbuck);
    scatterP2<<<dim3(nbuck), B, 0, stream>>>(ebuf, ocounts, rowstart, deg, csr, N, E, G, nbuck);
    // gathers
    gatherL1<<<dim3((N + 31) / 32), B, 0, stream>>>(csr, rowstart, deg, gmax1,
                                                    h1h, asrc1, adst1, eloop1,
                                                    b1, W2, a_src2, a_dst2,
                                                    h2pad, asrc2, adst2, eloop2, N);
    gmax2K<<<128, B, 0, stream>>>(asrc2, gmax2, N);
    gatherL2<<<dim3((N + 3) / 4), B, 0, stream>>>(csr, rowstart, deg, gmax2,
                                                  h2pad, adst2, eloop2, b2, out, N);
}

// Round 9
// 262.075 us; speedup vs baseline: 7.7711x; 1.2184x over previous
//
#include <hip/hip_runtime.h>
#include <hip/hip_fp16.h>
#include <math.h>

#define NEG_SLOPE 0.2f
__device__ __forceinline__ float lrelu(float x) { return x > 0.f ? x : NEG_SLOPE * x; }

// Order-preserving float<->uint encoding so unsigned atomicMax == float max.
__device__ __forceinline__ unsigned encf(float f) {
    unsigned u = __float_as_uint(f);
    return (u & 0x80000000u) ? ~u : (u | 0x80000000u);
}
__device__ __forceinline__ float decf(unsigned u) {
    return __uint_as_float((u & 0x80000000u) ? (u ^ 0x80000000u) : ~u);
}

// Phase A: h1 = x @ W1 [N,64] (stored fp16); alpha_src/dst [N,4]; self-loop logit.
// Block 0 also zeroes the gmax accumulators.
__global__ void phaseA(const float* __restrict__ x, const float* __restrict__ W1,
                       const float* __restrict__ a_src, const float* __restrict__ a_dst,
                       __half* __restrict__ h1h, float* __restrict__ asrc1,
                       float* __restrict__ adst1, float* __restrict__ eloop1,
                       unsigned* __restrict__ gmax1, unsigned* __restrict__ gmax2, int N) {
    if (blockIdx.x == 0 && threadIdx.x < 5) {
        if (threadIdx.x < 4) gmax1[threadIdx.x] = 0u;
        else gmax2[0] = 0u;
    }
    int node = blockIdx.x * 4 + (threadIdx.x >> 6);
    if (node >= N) return;
    int lane = threadIdx.x & 63;
    int head = lane >> 4, c = lane & 15;

    float h = 0.f;
    #pragma unroll
    for (int k = 0; k < 7; k++) h += x[node * 7 + k] * W1[k * 64 + lane];

    float ho = __shfl_xor(h, 1);
    if (!(lane & 1)) {
        __half2 hp = __floats2half2_rn(h, ho);
        ((__half2*)h1h)[(size_t)node * 32 + (lane >> 1)] = hp;
    }

    float s = h * a_src[lane];
    float d = h * a_dst[lane];
    #pragma unroll
    for (int m = 8; m >= 1; m >>= 1) {
        s += __shfl_xor(s, m);
        d += __shfl_xor(d, m);
    }
    if (c == 0) {
        asrc1[node * 4 + head] = s;
        adst1[node * 4 + head] = d;
        eloop1[node * 4 + head] = lrelu(s + d);
    }
}

// Global per-head max of asrc1 [N,4] -> gmax1[4] (encoded).
__global__ void gmax1K(const float* __restrict__ asrc1, unsigned* __restrict__ gmax1, int N) {
    float m0 = -1e30f, m1 = -1e30f, m2 = -1e30f, m3 = -1e30f;
    for (int i = blockIdx.x * blockDim.x + threadIdx.x; i < N; i += gridDim.x * blockDim.x) {
        float4 v = ((const float4*)asrc1)[i];
        m0 = fmaxf(m0, v.x); m1 = fmaxf(m1, v.y);
        m2 = fmaxf(m2, v.z); m3 = fmaxf(m3, v.w);
    }
    #pragma unroll
    for (int mm = 32; mm >= 1; mm >>= 1) {
        m0 = fmaxf(m0, __shfl_xor(m0, mm));
        m1 = fmaxf(m1, __shfl_xor(m1, mm));
        m2 = fmaxf(m2, __shfl_xor(m2, mm));
        m3 = fmaxf(m3, __shfl_xor(m3, mm));
    }
    if ((threadIdx.x & 63) == 0) {
        atomicMax(&gmax1[0], encf(m0));
        atomicMax(&gmax1[1], encf(m1));
        atomicMax(&gmax1[2], encf(m2));
        atomicMax(&gmax1[3], encf(m3));
    }
}

__global__ void gmax2K(const float* __restrict__ asrc2, unsigned* __restrict__ gmax2, int N) {
    float m0 = -1e30f;
    for (int i = blockIdx.x * blockDim.x + threadIdx.x; i < N; i += gridDim.x * blockDim.x)
        m0 = fmaxf(m0, asrc2[i]);
    #pragma unroll
    for (int mm = 32; mm >= 1; mm >>= 1) m0 = fmaxf(m0, __shfl_xor(m0, mm));
    if ((threadIdx.x & 63) == 0) atomicMax(gmax2, encf(m0));
}

// Generic exclusive scan, 3 kernels (n up to 262144).
__global__ void scan1(const int* __restrict__ in, int* __restrict__ outv,
                      int* __restrict__ blockSum, int n) {
    __shared__ int sm[256];
    int tid = threadIdx.x;
    int i = blockIdx.x * 256 + tid;
    int v = (i < n) ? in[i] : 0;
    sm[tid] = v;
    __syncthreads();
    for (int off = 1; off < 256; off <<= 1) {
        int t = sm[tid];
        int add = (tid >= off) ? sm[tid - off] : 0;
        __syncthreads();
        sm[tid] = t + add;
        __syncthreads();
    }
    if (i < n) outv[i] = sm[tid] - v;     // exclusive
    if (tid == 255) blockSum[blockIdx.x] = sm[255];
}

__global__ void scan2(int* __restrict__ blockSum, int nb) {
    __shared__ int sm[1024];
    int tid = threadIdx.x;
    int v = (tid < nb) ? blockSum[tid] : 0;
    sm[tid] = v;
    __syncthreads();
    for (int off = 1; off < 1024; off <<= 1) {
        int t = sm[tid];
        int add = (tid >= off) ? sm[tid - off] : 0;
        __syncthreads();
        sm[tid] = t + add;
        __syncthreads();
    }
    if (tid < nb) blockSum[tid] = sm[tid] - v;  // exclusive
}

__global__ void scan3(int* __restrict__ outv, const int* __restrict__ blockSum, int n) {
    int i = blockIdx.x * 256 + threadIdx.x;
    if (i < n) outv[i] += blockSum[blockIdx.x];
}

// --- Block-ordered counting sort of edges into 128-node dst-buckets ---
__global__ void histT(const int* __restrict__ dst, int* __restrict__ counts,
                      int E, int nbuck) {
    __shared__ int hist[1024];
    for (int j = threadIdx.x; j < nbuck; j += blockDim.x) hist[j] = 0;
    __syncthreads();
    int per = (E + gridDim.x - 1) / gridDim.x;
    int i0 = blockIdx.x * per, i1 = min(E, i0 + per);
    for (int i = i0 + threadIdx.x; i < i1; i += blockDim.x)
        atomicAdd(&hist[dst[i] >> 7], 1);
    __syncthreads();
    for (int j = threadIdx.x; j < nbuck; j += blockDim.x)
        counts[j * gridDim.x + blockIdx.x] = hist[j];
}

// scatterS: LDS cursors seeded from scanned offsets; LDS atomics only.
// ebuf entry packed: src (17b) | local-node-id (7b) << 17.
__global__ void scatterS(const int* __restrict__ src, const int* __restrict__ dst,
                         const int* __restrict__ ocounts, int* __restrict__ ebuf,
                         int E, int nbuck) {
    __shared__ int cur[1024];
    for (int j = threadIdx.x; j < nbuck; j += blockDim.x)
        cur[j] = ocounts[j * gridDim.x + blockIdx.x];
    __syncthreads();
    int per = (E + gridDim.x - 1) / gridDim.x;
    int i0 = blockIdx.x * per, i1 = min(E, i0 + per);
    for (int i = i0 + threadIdx.x; i < i1; i += blockDim.x) {
        int d = dst[i];
        int b = d >> 7;
        int pos = atomicAdd(&cur[b], 1);
        ebuf[pos] = src[i] | ((d & 127) << 17);
    }
}

// Scatter P2: one workgroup per 128-node bucket. Bucket bases from ocounts.
// Pass 1 counts per-node edges in LDS; in-LDS scan gives rowstart/deg;
// pass 2 places edges into csr within this bucket's window on ONE CU.
__global__ void scatterP2(const int* __restrict__ ebuf, const int* __restrict__ ocounts,
                          int* __restrict__ rowstart, int* __restrict__ deg,
                          int* __restrict__ csr, int N, int E, int G, int nbuck) {
    int b = blockIdx.x;
    int beg = ocounts[b * G];
    int end = (b + 1 < nbuck) ? ocounts[(b + 1) * G] : E;
    int base = b << 7;
    int tid = threadIdx.x;
    __shared__ int cnt[128];
    __shared__ int sc[128];
    __shared__ int rloc[128];
    __shared__ int lcur[128];
    if (tid < 128) cnt[tid] = 0;
    __syncthreads();
    for (int i = beg + tid; i < end; i += blockDim.x)
        atomicAdd(&cnt[ebuf[i] >> 17], 1);
    __syncthreads();
    if (tid < 128) sc[tid] = cnt[tid];
    __syncthreads();
    for (int off = 1; off < 128; off <<= 1) {
        int t = (tid < 128) ? sc[tid] : 0;
        int add = (tid >= off && tid < 128) ? sc[tid - off] : 0;
        __syncthreads();
        if (tid < 128) sc[tid] = t + add;
        __syncthreads();
    }
    if (tid < 128) {
        int rs = beg + sc[tid] - cnt[tid];   // exclusive scan + bucket base
        rloc[tid] = rs;
        lcur[tid] = 0;
        int node = base + tid;
        if (node < N) { rowstart[node] = rs; deg[node] = cnt[tid]; }
    }
    __syncthreads();
    for (int i = beg + tid; i < end; i += blockDim.x) {
        int e = ebuf[i];
        int j = e >> 17;
        int pos = rloc[j] + atomicAdd(&lcur[j], 1);
        csr[pos] = e & 0x1FFFF;
    }
}

// Layer-1 gather: 8 lanes per node (lane t owns channels 8t..8t+7, head=t>>1),
// 8 nodes per wave -> 8 independent gather streams, depth-2 value prefetch.
// Fused epilogue: normalize, +b1, ELU, @W2, layer-2 logits, pack h2pad row.
__global__ void gatherL1(const int* __restrict__ csr, const int* __restrict__ rowstart,
                         const int* __restrict__ deg, const unsigned* __restrict__ gmax1,
                         const __half* __restrict__ h1h, const float* __restrict__ asrc1,
                         const float* __restrict__ adst1, const float* __restrict__ eloop1,
                         const float* __restrict__ b1, const float* __restrict__ W2,
                         const float* __restrict__ a_src2, const float* __restrict__ a_dst2,
                         float* __restrict__ h2pad, float* __restrict__ asrc2,
                         float* __restrict__ adst2, float* __restrict__ eloop2, int N) {
    int node = blockIdx.x * 32 + (threadIdx.x >> 3);
    if (node >= N) return;
    int t = threadIdx.x & 7;
    int head = t >> 1;

    int rs = rowstart[node], dg = deg[node];
    float adh = adst1[node * 4 + head];
    float el = eloop1[node * 4 + head];
    float m = lrelu(decf(gmax1[head]) + adh);   // upper bound on segment logits

    const uint4* h1v = (const uint4*)h1h;       // row = 8 uint4 (128B)
    float z0 = __expf(el - m);
    float den = z0;
    uint4 hv0 = h1v[(size_t)node * 8 + t];
    float2 f0 = __half22float2(*(const __half2*)&hv0.x);
    float2 f1 = __half22float2(*(const __half2*)&hv0.y);
    float2 f2 = __half22float2(*(const __half2*)&hv0.z);
    float2 f3 = __half22float2(*(const __half2*)&hv0.w);
    float a0 = z0 * f0.x, a1 = z0 * f0.y, a2 = z0 * f1.x, a3 = z0 * f1.y;
    float a4 = z0 * f2.x, a5 = z0 * f2.y, a6 = z0 * f3.x, a7 = z0 * f3.y;

    if (dg > 0) {
        int ke = rs + dg;
        int s = csr[rs];
        float av = asrc1[s * 4 + head];
        uint4 hr = h1v[(size_t)s * 8 + t];
        for (int k = rs; k < ke; ++k) {
            int kk = (k + 1 < ke) ? k + 1 : k;
            int s2 = csr[kk];
            float av2 = asrc1[s2 * 4 + head];
            uint4 hr2 = h1v[(size_t)s2 * 8 + t];
            float z = __expf(lrelu(av + adh) - m);
            den += z;
            float2 g0 = __half22float2(*(const __half2*)&hr.x);
            float2 g1 = __half22float2(*(const __half2*)&hr.y);
            float2 g2 = __half22float2(*(const __half2*)&hr.z);
            float2 g3 = __half22float2(*(const __half2*)&hr.w);
            a0 = fmaf(z, g0.x, a0); a1 = fmaf(z, g0.y, a1);
            a2 = fmaf(z, g1.x, a2); a3 = fmaf(z, g1.y, a3);
            a4 = fmaf(z, g2.x, a4); a5 = fmaf(z, g2.y, a5);
            a6 = fmaf(z, g3.x, a6); a7 = fmaf(z, g3.y, a7);
            av = av2; hr = hr2;
        }
    }

    float inv = 1.f / den;
    const float4* b1v = (const float4*)b1;
    float4 bA = b1v[t * 2], bB = b1v[t * 2 + 1];
    float v0 = a0 * inv + bA.x, v1 = a1 * inv + bA.y;
    float v2 = a2 * inv + bA.z, v3 = a3 * inv + bA.w;
    float v4 = a4 * inv + bB.x, v5 = a5 * inv + bB.y;
    float v6 = a6 * inv + bB.z, v7 = a7 * inv + bB.w;
    v0 = v0 > 0.f ? v0 : __expf(v0) - 1.f;
    v1 = v1 > 0.f ? v1 : __expf(v1) - 1.f;
    v2 = v2 > 0.f ? v2 : __expf(v2) - 1.f;
    v3 = v3 > 0.f ? v3 : __expf(v3) - 1.f;
    v4 = v4 > 0.f ? v4 : __expf(v4) - 1.f;
    v5 = v5 > 0.f ? v5 : __expf(v5) - 1.f;
    v6 = v6 > 0.f ? v6 : __expf(v6) - 1.f;
    v7 = v7 > 0.f ? v7 : __expf(v7) - 1.f;

    // h2 = v @ W2 (64->6): per-lane partial over 8 channels, reduce over 8 lanes
    float hh[6];
    #pragma unroll
    for (int c2 = 0; c2 < 6; c2++) {
        const float* Wc = &W2[(t * 8) * 6 + c2];
        float p = v0 * Wc[0] + v1 * Wc[6] + v2 * Wc[12] + v3 * Wc[18]
                + v4 * Wc[24] + v5 * Wc[30] + v6 * Wc[36] + v7 * Wc[42];
        #pragma unroll
        for (int mm = 4; mm >= 1; mm >>= 1) p += __shfl_xor(p, mm);
        hh[c2] = p;
    }
    float as = 0.f, ad = 0.f;
    #pragma unroll
    for (int c2 = 0; c2 < 6; c2++) {
        as += hh[c2] * a_src2[c2];
        ad += hh[c2] * a_dst2[c2];
    }
    if (t == 0) {
        #pragma unroll
        for (int c2 = 0; c2 < 6; c2++) h2pad[(size_t)node * 8 + c2] = hh[c2];
        h2pad[(size_t)node * 8 + 6] = as;   // asrc2 packed into the gather row
        asrc2[node] = as;
        adst2[node] = ad;
        eloop2[node] = lrelu(as + ad);
    }
}

// Layer-2 gather + log_softmax. Wave per node, lane per edge (64 in flight).
__global__ void gatherL2(const int* __restrict__ csr, const int* __restrict__ rowstart,
                         const int* __restrict__ deg, const unsigned* __restrict__ gmax2,
                         const float* __restrict__ h2pad, const float* __restrict__ adst2,
                         const float* __restrict__ eloop2,
                         const float* __restrict__ b2, float* __restrict__ out, int N) {
    int node = blockIdx.x * 4 + (threadIdx.x >> 6);
    if (node >= N) return;
    int lane = threadIdx.x & 63;
    int rs = rowstart[node], ke = rs + deg[node];

    float adn = adst2[node];
    float m = lrelu(decf(*gmax2) + adn);

    float den = 0.f;
    float a0 = 0.f, a1 = 0.f, a2 = 0.f, a3 = 0.f, a4 = 0.f, a5 = 0.f;
    if (lane == 0) {
        float z0 = __expf(eloop2[node] - m);
        den = z0;
        float4 lo = ((const float4*)h2pad)[(size_t)node * 2];
        float4 hi = ((const float4*)h2pad)[(size_t)node * 2 + 1];
        a0 = z0 * lo.x; a1 = z0 * lo.y; a2 = z0 * lo.z;
        a3 = z0 * lo.w; a4 = z0 * hi.x; a5 = z0 * hi.y;
    }
    for (int k = rs + lane; k < ke; k += 64) {
        int s = csr[k];
        float4 lo = ((const float4*)h2pad)[(size_t)s * 2];
        float4 hi = ((const float4*)h2pad)[(size_t)s * 2 + 1];
        float z = __expf(lrelu(hi.z + adn) - m);   // hi.z = asrc2[s]
        den += z;
        a0 = fmaf(z, lo.x, a0); a1 = fmaf(z, lo.y, a1); a2 = fmaf(z, lo.z, a2);
        a3 = fmaf(z, lo.w, a3); a4 = fmaf(z, hi.x, a4); a5 = fmaf(z, hi.y, a5);
    }
    #pragma unroll
    for (int mm = 32; mm >= 1; mm >>= 1) {
        den += __shfl_xor(den, mm);
        a0 += __shfl_xor(a0, mm); a1 += __shfl_xor(a1, mm); a2 += __shfl_xor(a2, mm);
        a3 += __shfl_xor(a3, mm); a4 += __shfl_xor(a4, mm); a5 += __shfl_xor(a5, mm);
    }
    if (lane == 0) {
        float inv = 1.f / den;
        float v[6] = { a0 * inv + b2[0], a1 * inv + b2[1], a2 * inv + b2[2],
                       a3 * inv + b2[3], a4 * inv + b2[4], a5 * inv + b2[5] };
        float mxv = -1e30f;
        #pragma unroll
        for (int cc = 0; cc < 6; cc++) mxv = fmaxf(mxv, v[cc]);
        float ssum = 0.f;
        #pragma unroll
        for (int cc = 0; cc < 6; cc++) ssum += __expf(v[cc] - mxv);
        float lse = mxv + logf(ssum);
        #pragma unroll
        for (int cc = 0; cc < 6; cc++) out[node * 6 + cc] = v[cc] - lse;
    }
}

extern "C" void kernel_launch(void* const* d_in, const int* in_sizes, int n_in,
                              void* d_out, int out_size, void* d_ws, size_t ws_size,
                              hipStream_t stream) {
    const float* x      = (const float*)d_in[0];
    const int*   ei     = (const int*)d_in[1];
    const float* W1     = (const float*)d_in[2];
    const float* a_src1 = (const float*)d_in[3];
    const float* a_dst1 = (const float*)d_in[4];
    const float* b1     = (const float*)d_in[5];
    const float* W2     = (const float*)d_in[6];
    const float* a_src2 = (const float*)d_in[7];
    const float* a_dst2 = (const float*)d_in[8];
    const float* b2     = (const float*)d_in[9];
    float* out = (float*)d_out;

    const int N = in_sizes[0] / 7;
    const int E = in_sizes[1] / 2;
    const int* src = ei;
    const int* dst = ei + E;
    const int nbuck = (N + 127) >> 7;
    const int G = 256;                      // sort blocks
    const int M = nbuck * G;                // counts entries (<= 262144)

    // Workspace layout
    float* w = (float*)d_ws;
    __half* h1h  = (__half*)w;  w += (size_t)N * 32;   // N*64 halves
    float* asrc1  = w;  w += (size_t)N * 4;
    float* adst1  = w;  w += (size_t)N * 4;
    float* eloop1 = w;  w += (size_t)N * 4;
    float* h2pad  = w;  w += (size_t)N * 8;
    float* asrc2  = w;  w += (size_t)N;
    float* adst2  = w;  w += (size_t)N;
    float* eloop2 = w;  w += (size_t)N;
    int* ip = (int*)w;
    int* ebuf     = ip; ip += E;
    int* deg      = ip; ip += N;
    int* rowstart = ip; ip += N;
    int* blockSum = ip; ip += 1024;
    int* csr      = ip; ip += E;
    int* counts   = ip; ip += M;
    int* ocounts  = ip; ip += M;
    unsigned* gmax1 = (unsigned*)ip; ip += 4;
    unsigned* gmax2 = (unsigned*)ip; ip += 4;

    const int B = 256;
    int nbM = (M + 255) / 256;

    phaseA<<<dim3((N + 3) / 4), B, 0, stream>>>(x, W1, a_src1, a_dst1, h1h, asrc1,
                                                adst1, eloop1, gmax1, gmax2, N);
    gmax1K<<<128, B, 0, stream>>>(asrc1, gmax1, N);
    // bucket counting sort: hist -> scan -> scatter (no global atomics)
    histT<<<dim3(G), 512, 0, stream>>>(dst, counts, E, nbuck);
    scan1<<<dim3(nbM), 256, 0, stream>>>(counts, ocounts, blockSum, M);
    scan2<<<1, 1024, 0, stream>>>(blockSum, nbM);
    scan3<<<dim3(nbM), 256, 0, stream>>>(ocounts, blockSum, M);
    scatterS<<<dim3(G), 512, 0, stream>>>(src, dst, ocounts, ebuf, E, nbuck);
    scatterP2<<<dim3(nbuck), B, 0, stream>>>(ebuf, ocounts, rowstart, deg, csr, N, E, G, nbuck);
    // gathers
    gatherL1<<<dim3((N + 31) / 32), B, 0, stream>>>(csr, rowstart, deg, gmax1,
                                                    h1h, asrc1, adst1, eloop1,
                                                    b1, W2, a_src2, a_dst2,
                                                    h2pad, asrc2, adst2, eloop2, N);
    gmax2K<<<128, B, 0, stream>>>(asrc2, gmax2, N);
    gatherL2<<<dim3((N + 3) / 4), B, 0, stream>>>(csr, rowstart, deg, gmax2,
                                                  h2pad, adst2, eloop2, b2, out, N);
}

// Round 10
// 247.165 us; speedup vs baseline: 8.2399x; 1.0603x over previous
//
#include <hip/hip_runtime.h>
#include <hip/hip_fp16.h>
#include <math.h>

#define NEG_SLOPE 0.2f
#define LCAP 8192   // LDS csr capacity per bucket (avg 4096, max ~4500)

__device__ __forceinline__ float lrelu(float x) { return x > 0.f ? x : NEG_SLOPE * x; }

// Order-preserving float<->uint encoding so unsigned atomicMax == float max.
__device__ __forceinline__ unsigned encf(float f) {
    unsigned u = __float_as_uint(f);
    return (u & 0x80000000u) ? ~u : (u | 0x80000000u);
}
__device__ __forceinline__ float decf(unsigned u) {
    return __uint_as_float((u & 0x80000000u) ? (u ^ 0x80000000u) : ~u);
}

// Phase A: h1 = x @ W1 [N,64] (stored fp16); alpha_src/dst [N,4]; self-loop logit.
// Block 0 also zeroes the gmax accumulators.
__global__ void phaseA(const float* __restrict__ x, const float* __restrict__ W1,
                       const float* __restrict__ a_src, const float* __restrict__ a_dst,
                       __half* __restrict__ h1h, float* __restrict__ asrc1,
                       float* __restrict__ adst1, float* __restrict__ eloop1,
                       unsigned* __restrict__ gmax1, unsigned* __restrict__ gmax2, int N) {
    if (blockIdx.x == 0 && threadIdx.x < 5) {
        if (threadIdx.x < 4) gmax1[threadIdx.x] = 0u;
        else gmax2[0] = 0u;
    }
    int node = blockIdx.x * 4 + (threadIdx.x >> 6);
    if (node >= N) return;
    int lane = threadIdx.x & 63;
    int head = lane >> 4, c = lane & 15;

    float h = 0.f;
    #pragma unroll
    for (int k = 0; k < 7; k++) h += x[node * 7 + k] * W1[k * 64 + lane];

    float ho = __shfl_xor(h, 1);
    if (!(lane & 1)) {
        __half2 hp = __floats2half2_rn(h, ho);
        ((__half2*)h1h)[(size_t)node * 32 + (lane >> 1)] = hp;
    }

    float s = h * a_src[lane];
    float d = h * a_dst[lane];
    #pragma unroll
    for (int m = 8; m >= 1; m >>= 1) {
        s += __shfl_xor(s, m);
        d += __shfl_xor(d, m);
    }
    if (c == 0) {
        asrc1[node * 4 + head] = s;
        adst1[node * 4 + head] = d;
        eloop1[node * 4 + head] = lrelu(s + d);
    }
}

// Global per-head max of asrc1 [N,4] -> gmax1[4] (encoded).
__global__ void gmax1K(const float* __restrict__ asrc1, unsigned* __restrict__ gmax1, int N) {
    float m0 = -1e30f, m1 = -1e30f, m2 = -1e30f, m3 = -1e30f;
    for (int i = blockIdx.x * blockDim.x + threadIdx.x; i < N; i += gridDim.x * blockDim.x) {
        float4 v = ((const float4*)asrc1)[i];
        m0 = fmaxf(m0, v.x); m1 = fmaxf(m1, v.y);
        m2 = fmaxf(m2, v.z); m3 = fmaxf(m3, v.w);
    }
    #pragma unroll
    for (int mm = 32; mm >= 1; mm >>= 1) {
        m0 = fmaxf(m0, __shfl_xor(m0, mm));
        m1 = fmaxf(m1, __shfl_xor(m1, mm));
        m2 = fmaxf(m2, __shfl_xor(m2, mm));
        m3 = fmaxf(m3, __shfl_xor(m3, mm));
    }
    if ((threadIdx.x & 63) == 0) {
        atomicMax(&gmax1[0], encf(m0));
        atomicMax(&gmax1[1], encf(m1));
        atomicMax(&gmax1[2], encf(m2));
        atomicMax(&gmax1[3], encf(m3));
    }
}

__global__ void gmax2K(const float* __restrict__ asrc2, unsigned* __restrict__ gmax2, int N) {
    float m0 = -1e30f;
    for (int i = blockIdx.x * blockDim.x + threadIdx.x; i < N; i += gridDim.x * blockDim.x)
        m0 = fmaxf(m0, asrc2[i]);
    #pragma unroll
    for (int mm = 32; mm >= 1; mm >>= 1) m0 = fmaxf(m0, __shfl_xor(m0, mm));
    if ((threadIdx.x & 63) == 0) atomicMax(gmax2, encf(m0));
}

// Generic exclusive scan, 3 kernels (n up to 262144).
__global__ void scan1(const int* __restrict__ in, int* __restrict__ outv,
                      int* __restrict__ blockSum, int n) {
    __shared__ int sm[256];
    int tid = threadIdx.x;
    int i = blockIdx.x * 256 + tid;
    int v = (i < n) ? in[i] : 0;
    sm[tid] = v;
    __syncthreads();
    for (int off = 1; off < 256; off <<= 1) {
        int t = sm[tid];
        int add = (tid >= off) ? sm[tid - off] : 0;
        __syncthreads();
        sm[tid] = t + add;
        __syncthreads();
    }
    if (i < n) outv[i] = sm[tid] - v;     // exclusive
    if (tid == 255) blockSum[blockIdx.x] = sm[255];
}

__global__ void scan2(int* __restrict__ blockSum, int nb) {
    __shared__ int sm[1024];
    int tid = threadIdx.x;
    int v = (tid < nb) ? blockSum[tid] : 0;
    sm[tid] = v;
    __syncthreads();
    for (int off = 1; off < 1024; off <<= 1) {
        int t = sm[tid];
        int add = (tid >= off) ? sm[tid - off] : 0;
        __syncthreads();
        sm[tid] = t + add;
        __syncthreads();
    }
    if (tid < nb) blockSum[tid] = sm[tid] - v;  // exclusive
}

__global__ void scan3(int* __restrict__ outv, const int* __restrict__ blockSum, int n) {
    int i = blockIdx.x * 256 + threadIdx.x;
    if (i < n) outv[i] += blockSum[blockIdx.x];
}

// --- Block-ordered counting sort of edges into 128-node dst-buckets ---
__global__ void histT(const int* __restrict__ dst, int* __restrict__ counts,
                      int E, int nbuck) {
    __shared__ int hist[1024];
    for (int j = threadIdx.x; j < nbuck; j += blockDim.x) hist[j] = 0;
    __syncthreads();
    int per = (E + gridDim.x - 1) / gridDim.x;
    int i0 = blockIdx.x * per, i1 = min(E, i0 + per);
    for (int i = i0 + threadIdx.x; i < i1; i += blockDim.x)
        atomicAdd(&hist[dst[i] >> 7], 1);
    __syncthreads();
    for (int j = threadIdx.x; j < nbuck; j += blockDim.x)
        counts[j * gridDim.x + blockIdx.x] = hist[j];
}

// scatterS: LDS cursors seeded from scanned offsets; LDS atomics only.
// ebuf entry packed: src (17b) | local-node-id (7b) << 17.
__global__ void scatterS(const int* __restrict__ src, const int* __restrict__ dst,
                         const int* __restrict__ ocounts, int* __restrict__ ebuf,
                         int E, int nbuck) {
    __shared__ int cur[1024];
    for (int j = threadIdx.x; j < nbuck; j += blockDim.x)
        cur[j] = ocounts[j * gridDim.x + blockIdx.x];
    __syncthreads();
    int per = (E + gridDim.x - 1) / gridDim.x;
    int i0 = blockIdx.x * per, i1 = min(E, i0 + per);
    for (int i = i0 + threadIdx.x; i < i1; i += blockDim.x) {
        int d = dst[i];
        int b = d >> 7;
        int pos = atomicAdd(&cur[b], 1);
        ebuf[pos] = src[i] | ((d & 127) << 17);
    }
}

// Fused scatterP2 + layer-1 gather. One 512-thread block per 128-node bucket.
// Phase 1: build the bucket's csr in LDS (and stream it to global for gatherL2),
// deriving rowstart/deg via in-LDS scan. Phase 2: gather for the 128 nodes,
// 8 lanes per node, reading the edge list from LDS.
__global__ void __launch_bounds__(512, 2)
fusedG1(const int* __restrict__ ebuf, const int* __restrict__ ocounts,
        const unsigned* __restrict__ gmax1,
        const __half* __restrict__ h1h, const float* __restrict__ asrc1,
        const float* __restrict__ adst1, const float* __restrict__ eloop1,
        const float* __restrict__ b1, const float* __restrict__ W2,
        const float* __restrict__ a_src2, const float* __restrict__ a_dst2,
        int* __restrict__ rowstart, int* __restrict__ deg, int* __restrict__ csr,
        float* __restrict__ h2pad, float* __restrict__ asrc2,
        float* __restrict__ adst2, float* __restrict__ eloop2,
        int N, int E, int G, int nbuck) {
    int b = blockIdx.x;
    int beg = ocounts[b * G];
    int end = (b + 1 < nbuck) ? ocounts[(b + 1) * G] : E;
    int base = b << 7;
    int tid = threadIdx.x;

    __shared__ int cnt[128], sc[128], rloc[128], lloc[128], lcur[128];
    __shared__ int lcsr[LCAP];

    if (tid < 128) cnt[tid] = 0;
    __syncthreads();
    for (int i = beg + tid; i < end; i += blockDim.x)
        atomicAdd(&cnt[ebuf[i] >> 17], 1);
    __syncthreads();
    if (tid < 128) sc[tid] = cnt[tid];
    __syncthreads();
    for (int off = 1; off < 128; off <<= 1) {
        int t = (tid < 128) ? sc[tid] : 0;
        int add = (tid >= off && tid < 128) ? sc[tid - off] : 0;
        __syncthreads();
        if (tid < 128) sc[tid] = t + add;
        __syncthreads();
    }
    if (tid < 128) {
        int ex = sc[tid] - cnt[tid];         // bucket-local exclusive scan
        lloc[tid] = ex;
        rloc[tid] = beg + ex;
        lcur[tid] = 0;
        int node = base + tid;
        if (node < N) { rowstart[node] = beg + ex; deg[node] = cnt[tid]; }
    }
    __syncthreads();
    for (int i = beg + tid; i < end; i += blockDim.x) {
        int e = ebuf[i];
        int j = e >> 17;
        int s = e & 0x1FFFF;
        int pos = atomicAdd(&lcur[j], 1);
        int li = lloc[j] + pos;
        if (li < LCAP) lcsr[li] = s;
        csr[rloc[j] + pos] = s;              // global copy for gatherL2
    }
    __syncthreads();

    // ---- Phase 2: layer-1 gather for the bucket's 128 nodes ----
    const uint4* h1v = (const uint4*)h1h;    // fp16 row = 8 uint4 (128B)
    int t = tid & 7;
    int head = t >> 1;
    #pragma unroll
    for (int half = 0; half < 2; ++half) {
        int nl = half * 64 + (tid >> 3);     // local node 0..127
        int node = base + nl;
        if (node >= N) continue;
        int rs = lloc[nl], dg = cnt[nl];
        int grs = rloc[nl];

        float adh = adst1[node * 4 + head];
        float el = eloop1[node * 4 + head];
        float m = lrelu(decf(gmax1[head]) + adh);

        float z0 = __expf(el - m);
        float den = z0;
        uint4 hv0 = h1v[(size_t)node * 8 + t];
        float2 f0 = __half22float2(*(const __half2*)&hv0.x);
        float2 f1 = __half22float2(*(const __half2*)&hv0.y);
        float2 f2 = __half22float2(*(const __half2*)&hv0.z);
        float2 f3 = __half22float2(*(const __half2*)&hv0.w);
        float a0 = z0 * f0.x, a1 = z0 * f0.y, a2 = z0 * f1.x, a3 = z0 * f1.y;
        float a4 = z0 * f2.x, a5 = z0 * f2.y, a6 = z0 * f3.x, a7 = z0 * f3.y;

        if (dg > 0) {
            int s = (rs < LCAP) ? lcsr[rs] : csr[grs];
            float av = asrc1[s * 4 + head];
            uint4 hr = h1v[(size_t)s * 8 + t];
            for (int k = 0; k < dg; ++k) {
                int kk = (k + 1 < dg) ? k + 1 : k;
                int li = rs + kk;
                int s2 = (li < LCAP) ? lcsr[li] : csr[grs + kk];
                float av2 = asrc1[s2 * 4 + head];
                uint4 hr2 = h1v[(size_t)s2 * 8 + t];
                float z = __expf(lrelu(av + adh) - m);
                den += z;
                float2 g0 = __half22float2(*(const __half2*)&hr.x);
                float2 g1 = __half22float2(*(const __half2*)&hr.y);
                float2 g2 = __half22float2(*(const __half2*)&hr.z);
                float2 g3 = __half22float2(*(const __half2*)&hr.w);
                a0 = fmaf(z, g0.x, a0); a1 = fmaf(z, g0.y, a1);
                a2 = fmaf(z, g1.x, a2); a3 = fmaf(z, g1.y, a3);
                a4 = fmaf(z, g2.x, a4); a5 = fmaf(z, g2.y, a5);
                a6 = fmaf(z, g3.x, a6); a7 = fmaf(z, g3.y, a7);
                av = av2; hr = hr2;
            }
        }

        float inv = 1.f / den;
        const float4* b1v = (const float4*)b1;
        float4 bA = b1v[t * 2], bB = b1v[t * 2 + 1];
        float v0 = a0 * inv + bA.x, v1 = a1 * inv + bA.y;
        float v2 = a2 * inv + bA.z, v3 = a3 * inv + bA.w;
        float v4 = a4 * inv + bB.x, v5 = a5 * inv + bB.y;
        float v6 = a6 * inv + bB.z, v7 = a7 * inv + bB.w;
        v0 = v0 > 0.f ? v0 : __expf(v0) - 1.f;
        v1 = v1 > 0.f ? v1 : __expf(v1) - 1.f;
        v2 = v2 > 0.f ? v2 : __expf(v2) - 1.f;
        v3 = v3 > 0.f ? v3 : __expf(v3) - 1.f;
        v4 = v4 > 0.f ? v4 : __expf(v4) - 1.f;
        v5 = v5 > 0.f ? v5 : __expf(v5) - 1.f;
        v6 = v6 > 0.f ? v6 : __expf(v6) - 1.f;
        v7 = v7 > 0.f ? v7 : __expf(v7) - 1.f;

        float hh[6];
        #pragma unroll
        for (int c2 = 0; c2 < 6; c2++) {
            const float* Wc = &W2[(t * 8) * 6 + c2];
            float p = v0 * Wc[0] + v1 * Wc[6] + v2 * Wc[12] + v3 * Wc[18]
                    + v4 * Wc[24] + v5 * Wc[30] + v6 * Wc[36] + v7 * Wc[42];
            #pragma unroll
            for (int mm = 4; mm >= 1; mm >>= 1) p += __shfl_xor(p, mm);
            hh[c2] = p;
        }
        float as = 0.f, ad = 0.f;
        #pragma unroll
        for (int c2 = 0; c2 < 6; c2++) {
            as += hh[c2] * a_src2[c2];
            ad += hh[c2] * a_dst2[c2];
        }
        if (t == 0) {
            #pragma unroll
            for (int c2 = 0; c2 < 6; c2++) h2pad[(size_t)node * 8 + c2] = hh[c2];
            h2pad[(size_t)node * 8 + 6] = as;
            asrc2[node] = as;
            adst2[node] = ad;
            eloop2[node] = lrelu(as + ad);
        }
    }
}

// Layer-2 gather + log_softmax. 32 lanes per node (2 nodes/wave, 8 per block).
__global__ void gatherL2(const int* __restrict__ csr, const int* __restrict__ rowstart,
                         const int* __restrict__ deg, const unsigned* __restrict__ gmax2,
                         const float* __restrict__ h2pad, const float* __restrict__ adst2,
                         const float* __restrict__ eloop2,
                         const float* __restrict__ b2, float* __restrict__ out, int N) {
    int node = blockIdx.x * 8 + (threadIdx.x >> 5);
    if (node >= N) return;
    int lane = threadIdx.x & 31;
    int rs = rowstart[node], ke = rs + deg[node];

    float adn = adst2[node];
    float m = lrelu(decf(*gmax2) + adn);

    float den = 0.f;
    float a0 = 0.f, a1 = 0.f, a2 = 0.f, a3 = 0.f, a4 = 0.f, a5 = 0.f;
    if (lane == 0) {
        float z0 = __expf(eloop2[node] - m);
        den = z0;
        float4 lo = ((const float4*)h2pad)[(size_t)node * 2];
        float4 hi = ((const float4*)h2pad)[(size_t)node * 2 + 1];
        a0 = z0 * lo.x; a1 = z0 * lo.y; a2 = z0 * lo.z;
        a3 = z0 * lo.w; a4 = z0 * hi.x; a5 = z0 * hi.y;
    }
    for (int k = rs + lane; k < ke; k += 32) {
        int s = csr[k];
        float4 lo = ((const float4*)h2pad)[(size_t)s * 2];
        float4 hi = ((const float4*)h2pad)[(size_t)s * 2 + 1];
        float z = __expf(lrelu(hi.z + adn) - m);   // hi.z = asrc2[s]
        den += z;
        a0 = fmaf(z, lo.x, a0); a1 = fmaf(z, lo.y, a1); a2 = fmaf(z, lo.z, a2);
        a3 = fmaf(z, lo.w, a3); a4 = fmaf(z, hi.x, a4); a5 = fmaf(z, hi.y, a5);
    }
    #pragma unroll
    for (int mm = 16; mm >= 1; mm >>= 1) {
        den += __shfl_xor(den, mm);
        a0 += __shfl_xor(a0, mm); a1 += __shfl_xor(a1, mm); a2 += __shfl_xor(a2, mm);
        a3 += __shfl_xor(a3, mm); a4 += __shfl_xor(a4, mm); a5 += __shfl_xor(a5, mm);
    }
    if (lane == 0) {
        float inv = 1.f / den;
        float v[6] = { a0 * inv + b2[0], a1 * inv + b2[1], a2 * inv + b2[2],
                       a3 * inv + b2[3], a4 * inv + b2[4], a5 * inv + b2[5] };
        float mxv = -1e30f;
        #pragma unroll
        for (int cc = 0; cc < 6; cc++) mxv = fmaxf(mxv, v[cc]);
        float ssum = 0.f;
        #pragma unroll
        for (int cc = 0; cc < 6; cc++) ssum += __expf(v[cc] - mxv);
        float lse = mxv + logf(ssum);
        #pragma unroll
        for (int cc = 0; cc < 6; cc++) out[node * 6 + cc] = v[cc] - lse;
    }
}

extern "C" void kernel_launch(void* const* d_in, const int* in_sizes, int n_in,
                              void* d_out, int out_size, void* d_ws, size_t ws_size,
                              hipStream_t stream) {
    const float* x      = (const float*)d_in[0];
    const int*   ei     = (const int*)d_in[1];
    const float* W1     = (const float*)d_in[2];
    const float* a_src1 = (const float*)d_in[3];
    const float* a_dst1 = (const float*)d_in[4];
    const float* b1     = (const float*)d_in[5];
    const float* W2     = (const float*)d_in[6];
    const float* a_src2 = (const float*)d_in[7];
    const float* a_dst2 = (const float*)d_in[8];
    const float* b2     = (const float*)d_in[9];
    float* out = (float*)d_out;

    const int N = in_sizes[0] / 7;
    const int E = in_sizes[1] / 2;
    const int* src = ei;
    const int* dst = ei + E;
    const int nbuck = (N + 127) >> 7;
    const int G = 256;                      // sort blocks
    const int M = nbuck * G;                // counts entries (<= 262144)

    // Workspace layout
    float* w = (float*)d_ws;
    __half* h1h  = (__half*)w;  w += (size_t)N * 32;   // N*64 halves
    float* asrc1  = w;  w += (size_t)N * 4;
    float* adst1  = w;  w += (size_t)N * 4;
    float* eloop1 = w;  w += (size_t)N * 4;
    float* h2pad  = w;  w += (size_t)N * 8;
    float* asrc2  = w;  w += (size_t)N;
    float* adst2  = w;  w += (size_t)N;
    float* eloop2 = w;  w += (size_t)N;
    int* ip = (int*)w;
    int* ebuf     = ip; ip += E;
    int* deg      = ip; ip += N;
    int* rowstart = ip; ip += N;
    int* blockSum = ip; ip += 1024;
    int* csr      = ip; ip += E;
    int* counts   = ip; ip += M;
    int* ocounts  = ip; ip += M;
    unsigned* gmax1 = (unsigned*)ip; ip += 4;
    unsigned* gmax2 = (unsigned*)ip; ip += 4;

    const int B = 256;
    int nbM = (M + 255) / 256;

    phaseA<<<dim3((N + 3) / 4), B, 0, stream>>>(x, W1, a_src1, a_dst1, h1h, asrc1,
                                                adst1, eloop1, gmax1, gmax2, N);
    gmax1K<<<128, B, 0, stream>>>(asrc1, gmax1, N);
    // bucket counting sort: hist -> scan -> scatter (no global atomics)
    histT<<<dim3(G), 512, 0, stream>>>(dst, counts, E, nbuck);
    scan1<<<dim3(nbM), 256, 0, stream>>>(counts, ocounts, blockSum, M);
    scan2<<<1, 1024, 0, stream>>>(blockSum, nbM);
    scan3<<<dim3(nbM), 256, 0, stream>>>(ocounts, blockSum, M);
    scatterS<<<dim3(G), 512, 0, stream>>>(src, dst, ocounts, ebuf, E, nbuck);
    // fused csr-build + layer-1 gather (bucket-resident)
    fusedG1<<<dim3(nbuck), 512, 0, stream>>>(ebuf, ocounts, gmax1,
                                             h1h, asrc1, adst1, eloop1,
                                             b1, W2, a_src2, a_dst2,
                                             rowstart, deg, csr,
                                             h2pad, asrc2, adst2, eloop2,
                                             N, E, G, nbuck);
    gmax2K<<<128, B, 0, stream>>>(asrc2, gmax2, N);
    gatherL2<<<dim3((N + 7) / 8), B, 0, stream>>>(csr, rowstart, deg, gmax2,
                                                  h2pad, adst2, eloop2, b2, out, N);
}